// Round 2
// baseline (3142.132 us; speedup 1.0000x reference)
//
#include <hip/hip_runtime.h>
#include <hip/hip_bf16.h>
#include <math.h>

#define NN 100000
#define EE 1600000
#define INC 256
#define HH 64
#define OUTC 40

typedef __hip_bfloat16 bf16;

__device__ __forceinline__ bf16 f2bf(float f){ return __float2bfloat16(f); }
__device__ __forceinline__ float lo_f(unsigned u){ union{unsigned x;float f;}c; c.x = u<<16; return c.f; }
__device__ __forceinline__ float hi_f(unsigned u){ union{unsigned x;float f;}c; c.x = u & 0xffff0000u; return c.f; }

__device__ __forceinline__ float wsum(float v){
  #pragma unroll
  for(int m=1;m<64;m<<=1) v += __shfl_xor(v,m);
  return v;
}

// ---------------- degree / norm ----------------
__global__ void k_deg_init(float* deg){
  int i = blockIdx.x*blockDim.x + threadIdx.x;
  if (i < NN) deg[i] = 1.0f;   // self loop
}
__global__ void k_deg_count(const int* __restrict__ ei, float* deg){
  int e = blockIdx.x*blockDim.x + threadIdx.x;
  if (e < EE) unsafeAtomicAdd(&deg[ei[EE + e]], 1.0f);
}
__global__ void k_dinv(float* deg){
  int i = blockIdx.x*blockDim.x + threadIdx.x;
  if (i < NN) deg[i] = rsqrtf(deg[i]);
}
__global__ void k_norm(const int* __restrict__ ei, const float* __restrict__ dinv,
                       float* __restrict__ nrm){
  int e = blockIdx.x*blockDim.x + threadIdx.x;
  if (e < EE) nrm[e] = dinv[ei[e]] * dinv[ei[EE + e]];
}

// ---------------- h0 = relu(x @ W_in^T + b_in) ----------------
__global__ void __launch_bounds__(256) k_h0(const float* __restrict__ x,
                                            const float* __restrict__ Win,
                                            const float* __restrict__ bin,
                                            float* __restrict__ tok0){
  __shared__ float2 Wt[128*64];   // [k2][h], pairs along K   (64 KB)
  __shared__ float xs[4][256];
  __shared__ float bs[64];
  const int tid = threadIdx.x;
  const float2* w2 = (const float2*)Win;   // Win[h][k] row-major: w2[h*128 + k2]
  for (int idx = tid; idx < 64*128; idx += 256){
    int h = idx >> 7, k2 = idx & 127;
    Wt[k2*64 + h] = w2[idx];
  }
  if (tid < 64) bs[tid] = bin[tid];
  __syncthreads();
  const int w = tid >> 6, l = tid & 63;
  for (int g = blockIdx.x; g < NN/4; g += gridDim.x){
    __syncthreads();
    { // stage 4 rows of x (1024 floats), float4 per thread
      float4 v = *(const float4*)(x + (size_t)g*1024 + tid*4);
      int r = tid >> 6, c = (tid & 63)*4;
      xs[r][c] = v.x; xs[r][c+1] = v.y; xs[r][c+2] = v.z; xs[r][c+3] = v.w;
    }
    __syncthreads();
    float acc = bs[l];
    const float2* xr = (const float2*)xs[w];
    #pragma unroll 8
    for (int k2 = 0; k2 < 128; ++k2){
      float2 xv = xr[k2];
      float2 wv = Wt[k2*64 + l];
      acc += xv.x*wv.x + xv.y*wv.y;
    }
    tok0[(size_t)(g*4 + w)*64 + l] = fmaxf(acc, 0.f);
  }
}

// ---------------- propagation ----------------
__global__ void k_self_init(const float* __restrict__ prev, const float* __restrict__ dinv,
                            float* __restrict__ cur){
  int i = blockIdx.x*blockDim.x + threadIdx.x;
  if (i < NN*HH){
    float d = dinv[i >> 6];
    cur[i] = prev[i] * d * d;
  }
}
__global__ void k_scatter(const int* __restrict__ ei, const float* __restrict__ nrm,
                          const float* __restrict__ prev, float* __restrict__ cur){
  int t = blockIdx.x*blockDim.x + threadIdx.x;
  int lane = t & 63;
  int wid  = t >> 6;
  int nw   = (gridDim.x * blockDim.x) >> 6;
  for (int e = wid; e < EE; e += nw){
    int s = ei[e], d = ei[EE + e];
    float wv = nrm[e];
    float v = prev[(size_t)s*64 + lane] * wv;
    unsafeAtomicAdd(&cur[(size_t)d*64 + lane], v);
  }
}

// ---------------- token = relu(p @ sgW^T + sgb) ----------------
__global__ void __launch_bounds__(256) k_token(const float* __restrict__ cur,
                                               const float* __restrict__ sgW,
                                               const float* __restrict__ sgb,
                                               float* __restrict__ tok){
  __shared__ float2 Wt[32*64];    // [j2][h]  (16 KB)
  __shared__ float xs[256];
  __shared__ float bs[64];
  const int tid = threadIdx.x;
  const float2* w2 = (const float2*)sgW;   // sgW[h][k]: w2[h*32 + j2]
  for (int idx = tid; idx < 64*32; idx += 256){
    int h = idx >> 5, j2 = idx & 31;
    Wt[j2*64 + h] = w2[idx];
  }
  if (tid < 64) bs[tid] = sgb[tid];
  __syncthreads();
  const int w = tid >> 6, l = tid & 63;
  for (int g = blockIdx.x; g < NN/4; g += gridDim.x){
    __syncthreads();
    xs[tid] = cur[(size_t)g*256 + tid];
    __syncthreads();
    float acc = bs[l];
    const float2* xr = (const float2*)(xs + w*64);
    #pragma unroll
    for (int j2 = 0; j2 < 32; ++j2){
      float2 xv = xr[j2];
      float2 wv = Wt[j2*64 + l];
      acc += xv.x*wv.x + xv.y*wv.y;
    }
    tok[(size_t)(g*4 + w)*64 + l] = fmaxf(acc, 0.f);
  }
}

// ---------------- attention + LN1 (in-place on tokens) ----------------
__global__ void __launch_bounds__(256) k_attn(float* __restrict__ tokens,
    const float* __restrict__ Wqkv, const float* __restrict__ bqkv,
    const float* __restrict__ Wo,   const float* __restrict__ bo,
    const float* __restrict__ ln1w, const float* __restrict__ ln1b){
  __shared__ float2 Wq[32*192];   // [j2][r]  (48 KB)
  __shared__ float2 Wop[32*64];   // (16 KB)
  __shared__ float bq[192], bof[64], l1w[64], l1b[64];
  __shared__ float seqs[4][4][64];
  __shared__ float as_[4][4][64];
  const int tid = threadIdx.x;
  {
    const float2* w2 = (const float2*)Wqkv;   // [r][j2], 192 x 32
    for (int idx = tid; idx < 192*32; idx += 256){
      int r = idx >> 5, j2 = idx & 31;
      Wq[j2*192 + r] = w2[idx];
    }
    const float2* o2 = (const float2*)Wo;     // [r][j2], 64 x 32
    for (int idx = tid; idx < 64*32; idx += 256){
      int r = idx >> 5, j2 = idx & 31;
      Wop[j2*64 + r] = o2[idx];
    }
    if (tid < 192) bq[tid] = bqkv[tid];
    if (tid < 64){ bof[tid]=bo[tid]; l1w[tid]=ln1w[tid]; l1b[tid]=ln1b[tid]; }
  }
  __syncthreads();
  const int w = tid >> 6, l = tid & 63;
  for (int g = blockIdx.x; g < NN/4; g += gridDim.x){
    int n = g*4 + w;
    float seq_l[4];
    #pragma unroll
    for (int t = 0; t < 4; ++t){
      seq_l[t] = tokens[(size_t)t*NN*64 + (size_t)n*64 + l];
      seqs[w][t][l] = seq_l[t];
    }
    float q_l[4], k_l[4], v_l[4];
    #pragma unroll
    for (int t = 0; t < 4; ++t){
      const float2* sr = (const float2*)seqs[w][t];
      #pragma unroll
      for (int part = 0; part < 3; ++part){
        int r = part*64 + l;
        float acc = bq[r];
        #pragma unroll 8
        for (int j2 = 0; j2 < 32; ++j2){
          float2 sv = sr[j2];
          float2 wv = Wq[j2*192 + r];
          acc += sv.x*wv.x + sv.y*wv.y;
        }
        if (part == 0) q_l[t] = acc; else if (part == 1) k_l[t] = acc; else v_l[t] = acc;
      }
    }
    // scores + softmax (replicated across lanes)
    float p[4][4];
    #pragma unroll
    for (int s = 0; s < 4; ++s){
      float sc[4];
      #pragma unroll
      for (int t = 0; t < 4; ++t) sc[t] = wsum(q_l[s]*k_l[t]) * 0.125f;
      float m = fmaxf(fmaxf(sc[0],sc[1]), fmaxf(sc[2],sc[3]));
      float den = 0.f;
      #pragma unroll
      for (int t = 0; t < 4; ++t){ sc[t] = __expf(sc[t]-m); den += sc[t]; }
      float inv = 1.f/den;
      #pragma unroll
      for (int t = 0; t < 4; ++t) p[s][t] = sc[t]*inv;
    }
    #pragma unroll
    for (int s = 0; s < 4; ++s){
      float a = p[s][0]*v_l[0] + p[s][1]*v_l[1] + p[s][2]*v_l[2] + p[s][3]*v_l[3];
      as_[w][s][l] = a;
    }
    // out proj + residual + LN1
    #pragma unroll
    for (int s = 0; s < 4; ++s){
      float acc = bof[l];
      const float2* ar = (const float2*)as_[w][s];
      #pragma unroll 8
      for (int j2 = 0; j2 < 32; ++j2){
        float2 av = ar[j2];
        float2 wv = Wop[j2*64 + l];
        acc += av.x*wv.x + av.y*wv.y;
      }
      float xv = seq_l[s] + acc;
      float mean = wsum(xv) * (1.f/64.f);
      float d = xv - mean;
      float var = wsum(d*d) * (1.f/64.f);
      float y = d * rsqrtf(var + 1e-5f) * l1w[l] + l1b[l];
      tokens[(size_t)s*NN*64 + (size_t)n*64 + l] = y;
    }
  }
}

// ---------------- FFN + LN2 + mean + classifier ----------------
__global__ void __launch_bounds__(256) k_ffn(const float* __restrict__ tokens,
    const float* __restrict__ W1, const float* __restrict__ b1,
    const float* __restrict__ W2, const float* __restrict__ b2,
    const float* __restrict__ ln2w, const float* __restrict__ ln2b,
    const float* __restrict__ Wc, const float* __restrict__ bc,
    float* __restrict__ out){
  __shared__ float2 W1t[32*128];  // [j2][r<128]  (32 KB)
  __shared__ float2 W2t[64*64];   // [j2<64][r<64] (32 KB)
  __shared__ unsigned Wcp[32*40]; // [j2][o<40] packed bf16 pairs (5 KB)
  __shared__ float b1s[128], b2s[64], l2w[64], l2b[64], bcs[40];
  __shared__ float seqs[4][4][64];
  __shared__ float f1s[4][128];   // per-wave, current token
  __shared__ float hs[4][64];
  const int tid = threadIdx.x;
  {
    const float2* w2 = (const float2*)W1;     // [r][j2], 128 x 32
    for (int idx = tid; idx < 128*32; idx += 256){
      int r = idx >> 5, j2 = idx & 31;
      W1t[j2*128 + r] = w2[idx];
    }
    const float2* v2 = (const float2*)W2;     // [r][j2], 64 x 64
    for (int idx = tid; idx < 64*64; idx += 256){
      int r = idx >> 6, j2 = idx & 63;
      W2t[j2*64 + r] = v2[idx];
    }
    for (int idx = tid; idx < 40*32; idx += 256){
      int o = idx >> 5, j2 = idx & 31;
      bf16 ba = f2bf(Wc[o*64 + 2*j2]);
      bf16 bb = f2bf(Wc[o*64 + 2*j2 + 1]);
      unsigned ua = *(const unsigned short*)&ba;
      unsigned ub = *(const unsigned short*)&bb;
      Wcp[j2*40 + o] = (ub << 16) | ua;
    }
    if (tid < 128) b1s[tid] = b1[tid];
    if (tid < 64){ b2s[tid]=b2[tid]; l2w[tid]=ln2w[tid]; l2b[tid]=ln2b[tid]; }
    if (tid < 40)  bcs[tid] = bc[tid];
  }
  __syncthreads();
  const int w = tid >> 6, l = tid & 63;
  for (int g = blockIdx.x; g < NN/4; g += gridDim.x){
    int n = g*4 + w;
    float seq_l[4];
    #pragma unroll
    for (int t = 0; t < 4; ++t){
      seq_l[t] = tokens[(size_t)t*NN*64 + (size_t)n*64 + l];
      seqs[w][t][l] = seq_l[t];
    }
    float hacc = 0.f;
    #pragma unroll
    for (int t = 0; t < 4; ++t){
      // ff1 + exact gelu (lane l computes rows l and l+64)
      const float2* sr = (const float2*)seqs[w][t];
      #pragma unroll
      for (int part = 0; part < 2; ++part){
        int r = part*64 + l;
        float acc = b1s[r];
        #pragma unroll 8
        for (int j2 = 0; j2 < 32; ++j2){
          float2 sv = sr[j2];
          float2 wv = W1t[j2*128 + r];
          acc += sv.x*wv.x + sv.y*wv.y;
        }
        f1s[w][r] = 0.5f * acc * (1.f + erff(acc * 0.70710678118654752f));
      }
      // ff2 + residual + LN2 + token mean
      float acc = b2s[l];
      const float2* fr = (const float2*)f1s[w];
      #pragma unroll 8
      for (int j2 = 0; j2 < 64; ++j2){
        float2 fv = fr[j2];
        float2 wv = W2t[j2*64 + l];
        acc += fv.x*wv.x + fv.y*wv.y;
      }
      float xv = seq_l[t] + acc;
      float mean = wsum(xv) * (1.f/64.f);
      float d = xv - mean;
      float var = wsum(d*d) * (1.f/64.f);
      float y = d * rsqrtf(var + 1e-5f) * l2w[l] + l2b[l];
      hacc += y;
    }
    hs[w][l] = hacc * 0.25f;
    // classifier (lanes 0..39)
    if (l < OUTC){
      float acc = bcs[l];
      const float2* hr = (const float2*)hs[w];
      #pragma unroll 8
      for (int j2 = 0; j2 < 32; ++j2){
        float2 hv = hr[j2];
        unsigned u = Wcp[j2*40 + l];
        acc += hv.x * lo_f(u) + hv.y * hi_f(u);
      }
      out[(size_t)n*OUTC + l] = acc;
    }
  }
}

extern "C" void kernel_launch(void* const* d_in, const int* in_sizes, int n_in,
                              void* d_out, int out_size, void* d_ws, size_t ws_size,
                              hipStream_t stream) {
  const float* x    = (const float*)d_in[0];
  const int*   ei   = (const int*  )d_in[1];
  const float* Win  = (const float*)d_in[2];
  const float* bin  = (const float*)d_in[3];
  const float* sgW  = (const float*)d_in[4];
  const float* sgb  = (const float*)d_in[5];
  const float* Wqkv = (const float*)d_in[6];
  const float* bqkv = (const float*)d_in[7];
  const float* Wo   = (const float*)d_in[8];
  const float* bo   = (const float*)d_in[9];
  const float* W1   = (const float*)d_in[10];
  const float* b1   = (const float*)d_in[11];
  const float* W2   = (const float*)d_in[12];
  const float* b2   = (const float*)d_in[13];
  const float* ln1w = (const float*)d_in[14];
  const float* ln1b = (const float*)d_in[15];
  const float* ln2w = (const float*)d_in[16];
  const float* ln2b = (const float*)d_in[17];
  const float* Wc   = (const float*)d_in[18];
  const float* bc   = (const float*)d_in[19];

  char* ws = (char*)d_ws;
  float* deg    = (float*)(ws);                    // 400,000 B
  float* nrm    = (float*)(ws + 400128);           // 6,400,000 B
  float* tokens = (float*)(ws + 6800128);          // 4*N*64*4 = 102,400,000 B
  float* pbuf0  = (float*)(ws + 109200128);        // 25,600,000 B
  float* pbuf1  = (float*)(ws + 134800128);        // 25,600,000 B

  k_deg_init<<<(NN+255)/256, 256, 0, stream>>>(deg);
  k_deg_count<<<(EE+255)/256, 256, 0, stream>>>(ei, deg);
  k_dinv<<<(NN+255)/256, 256, 0, stream>>>(deg);
  k_norm<<<(EE+255)/256, 256, 0, stream>>>(ei, deg, nrm);

  k_h0<<<2048, 256, 0, stream>>>(x, Win, bin, tokens);

  float* pbufs[2] = { pbuf0, pbuf1 };
  for (int k = 0; k < 3; ++k){
    const float* prev = (k == 0) ? tokens : pbufs[(k+1) & 1];
    float* cur = pbufs[k & 1];
    k_self_init<<<(NN*HH+255)/256, 256, 0, stream>>>(prev, deg, cur);
    k_scatter<<<8192, 256, 0, stream>>>(ei, nrm, prev, cur);
    k_token<<<2048, 256, 0, stream>>>(cur, sgW + (size_t)k*HH*HH, sgb + (size_t)k*HH,
                                      tokens + (size_t)(k+1)*NN*HH);
  }

  k_attn<<<2048, 256, 0, stream>>>(tokens, Wqkv, bqkv, Wo, bo, ln1w, ln1b);
  k_ffn<<<2048, 256, 0, stream>>>(tokens, W1, b1, W2, b2, ln2w, ln2b, Wc, bc,
                                  (float*)d_out);
}

// Round 3
// 1643.259 us; speedup vs baseline: 1.9121x; 1.9121x over previous
//
#include <hip/hip_runtime.h>
#include <hip/hip_bf16.h>
#include <math.h>

#define NN 100000
#define EE 1600000
#define OUTC 40

typedef __hip_bfloat16 bf16;
typedef __attribute__((ext_vector_type(8))) short bf16x8;
typedef __attribute__((ext_vector_type(4))) float f32x4;

__device__ __forceinline__ unsigned short f2us(float f){
  bf16 b = __float2bfloat16(f);
  unsigned short u; __builtin_memcpy(&u, &b, 2); return u;
}
__device__ __forceinline__ float us2f(unsigned short u){
  union{unsigned x; float f;} c; c.x = ((unsigned)u)<<16; return c.f;
}
__device__ __forceinline__ float lo_f(unsigned u){ union{unsigned x;float f;}c; c.x = u<<16; return c.f; }
__device__ __forceinline__ float hi_f(unsigned u){ union{unsigned x;float f;}c; c.x = u & 0xffff0000u; return c.f; }

// ---------------- degree / norm ----------------
__global__ void k_deg_init(float* deg){
  int i = blockIdx.x*blockDim.x + threadIdx.x;
  if (i < NN) deg[i] = 1.0f;   // self loop
}
__global__ void k_deg_count(const int* __restrict__ ei, float* deg){
  int e = blockIdx.x*blockDim.x + threadIdx.x;
  if (e < EE) unsafeAtomicAdd(&deg[ei[EE + e]], 1.0f);
}
__global__ void k_dinv(float* deg){
  int i = blockIdx.x*blockDim.x + threadIdx.x;
  if (i < NN) deg[i] = rsqrtf(deg[i]);
}
__global__ void k_norm(const int* __restrict__ ei, const float* __restrict__ dinv,
                       float* __restrict__ nrm){
  int e = blockIdx.x*blockDim.x + threadIdx.x;
  if (e < EE) nrm[e] = dinv[ei[e]] * dinv[ei[EE + e]];
}

// ---------------- h0 = relu(x @ W_in^T + b_in); cur1 = h0*d^2 ----------------
__global__ void __launch_bounds__(256) k_h0(const float* __restrict__ x,
    const float* __restrict__ Win, const float* __restrict__ bin,
    const float* __restrict__ dinv,
    float* __restrict__ tok0, float* __restrict__ cur1){
  __shared__ unsigned short Xs[64*264];
  __shared__ unsigned short Ws[64*264];
  __shared__ float bs[64];
  const int tid = threadIdx.x;
  for (int idx = tid; idx < 4096; idx += 256){       // Win: 64x256
    int r = idx >> 6, c0 = (idx & 63) * 4;
    float4 v = *(const float4*)(Win + r*256 + c0);
    unsigned short* d = &Ws[r*264 + c0];
    d[0]=f2us(v.x); d[1]=f2us(v.y); d[2]=f2us(v.z); d[3]=f2us(v.w);
  }
  const int n0 = blockIdx.x * 64;
  for (int idx = tid; idx < 4096; idx += 256){       // X tile: 64x256
    int r = idx >> 6, c0 = (idx & 63) * 4;
    int n = n0 + r; if (n >= NN) n = NN-1;
    float4 v = *(const float4*)(x + (size_t)n*256 + c0);
    unsigned short* d = &Xs[r*264 + c0];
    d[0]=f2us(v.x); d[1]=f2us(v.y); d[2]=f2us(v.z); d[3]=f2us(v.w);
  }
  if (tid < 64) bs[tid] = bin[tid];
  __syncthreads();
  const int w = tid >> 6, lane = tid & 63, quad = lane >> 4, c = lane & 15;
  f32x4 acc[4] = {{0,0,0,0},{0,0,0,0},{0,0,0,0},{0,0,0,0}};
  #pragma unroll
  for (int ks = 0; ks < 8; ++ks){
    int k0 = ks*32 + quad*8;
    bf16x8 a = *(const bf16x8*)&Xs[(w*16 + c)*264 + k0];
    #pragma unroll
    for (int nt = 0; nt < 4; ++nt){
      bf16x8 b = *(const bf16x8*)&Ws[(nt*16 + c)*264 + k0];
      acc[nt] = __builtin_amdgcn_mfma_f32_16x16x32_bf16(a, b, acc[nt], 0,0,0);
    }
  }
  #pragma unroll
  for (int nt = 0; nt < 4; ++nt){
    int col = nt*16 + c;
    float bb = bs[col];
    #pragma unroll
    for (int rg = 0; rg < 4; ++rg){
      int n = n0 + w*16 + quad*4 + rg;
      if (n < NN){
        float v = fmaxf(acc[nt][rg] + bb, 0.f);
        tok0[(size_t)n*64 + col] = v;
        float d = dinv[n];
        cur1[(size_t)n*64 + col] = v*d*d;
      }
    }
  }
}

// ---------------- scatter (unchanged) ----------------
__global__ void k_scatter(const int* __restrict__ ei, const float* __restrict__ nrm,
                          const float* __restrict__ prev, float* __restrict__ cur){
  int t = blockIdx.x*blockDim.x + threadIdx.x;
  int lane = t & 63;
  int wid  = t >> 6;
  int nw   = (gridDim.x * blockDim.x) >> 6;
  for (int e = wid; e < EE; e += nw){
    int s = ei[e], d = ei[EE + e];
    float wv = nrm[e];
    float v = prev[(size_t)s*64 + lane] * wv;
    unsafeAtomicAdd(&cur[(size_t)d*64 + lane], v);
  }
}

// ------- token = relu(cur @ sgW^T + sgb); optional nextInit = cur*d^2 -------
__global__ void __launch_bounds__(256) k_token(const float* __restrict__ cur,
    const float* __restrict__ sgW, const float* __restrict__ sgb,
    const float* __restrict__ dinv, float* __restrict__ tok,
    float* __restrict__ nextInit){
  __shared__ unsigned short Xs[64*72];
  __shared__ unsigned short Ws[64*72];
  __shared__ float bs[64];
  const int tid = threadIdx.x;
  for (int idx = tid; idx < 1024; idx += 256){       // sgW: 64x64
    int r = idx >> 4, c0 = (idx & 15)*4;
    float4 v = *(const float4*)(sgW + r*64 + c0);
    unsigned short* d = &Ws[r*72 + c0];
    d[0]=f2us(v.x); d[1]=f2us(v.y); d[2]=f2us(v.z); d[3]=f2us(v.w);
  }
  if (tid < 64) bs[tid] = sgb[tid];
  const int n0 = blockIdx.x*64;
  {
    int r = tid >> 2, c0 = (tid & 3)*16;
    int n = n0 + r; bool ok = (n < NN); int nc = ok ? n : NN-1;
    float dd = dinv[nc]; dd = dd*dd;
    #pragma unroll
    for (int i = 0; i < 4; ++i){
      float4 v = *(const float4*)(cur + (size_t)nc*64 + c0 + i*4);
      unsigned short* d = &Xs[r*72 + c0 + i*4];
      d[0]=f2us(v.x); d[1]=f2us(v.y); d[2]=f2us(v.z); d[3]=f2us(v.w);
      if (nextInit && ok){
        float4 o; o.x=v.x*dd; o.y=v.y*dd; o.z=v.z*dd; o.w=v.w*dd;
        *(float4*)(nextInit + (size_t)n*64 + c0 + i*4) = o;
      }
    }
  }
  __syncthreads();
  const int w = tid >> 6, lane = tid & 63, quad = lane >> 4, c = lane & 15;
  f32x4 acc[4] = {{0,0,0,0},{0,0,0,0},{0,0,0,0},{0,0,0,0}};
  #pragma unroll
  for (int ks = 0; ks < 2; ++ks){
    int k0 = ks*32 + quad*8;
    bf16x8 a = *(const bf16x8*)&Xs[(w*16 + c)*72 + k0];
    #pragma unroll
    for (int nt = 0; nt < 4; ++nt){
      bf16x8 b = *(const bf16x8*)&Ws[(nt*16 + c)*72 + k0];
      acc[nt] = __builtin_amdgcn_mfma_f32_16x16x32_bf16(a, b, acc[nt], 0,0,0);
    }
  }
  #pragma unroll
  for (int nt = 0; nt < 4; ++nt){
    int col = nt*16 + c;
    float bb = bs[col];
    #pragma unroll
    for (int rg = 0; rg < 4; ++rg){
      int n = n0 + w*16 + quad*4 + rg;
      if (n < NN) tok[(size_t)n*64 + col] = fmaxf(acc[nt][rg] + bb, 0.f);
    }
  }
}

// ---------------- attention + LN1 (MFMA, in-place on tokens) ----------------
__global__ void __launch_bounds__(256) k_attn(float* __restrict__ tokens,
    const float* __restrict__ Wqkv, const float* __restrict__ bqkv,
    const float* __restrict__ Wo,   const float* __restrict__ bo,
    const float* __restrict__ ln1w, const float* __restrict__ ln1b){
  __shared__ unsigned short Wq[192*72];
  __shared__ unsigned short Wos[64*72];
  __shared__ unsigned short Xs[64*72];
  __shared__ unsigned short As2[64*72];
  __shared__ float bq[192], bos[64], l1w[64], l1b[64];
  const int tid = threadIdx.x;
  for (int idx = tid; idx < 3072; idx += 256){       // Wqkv: 192x64
    int r = idx >> 4, c0 = (idx & 15)*4;
    float4 v = *(const float4*)(Wqkv + r*64 + c0);
    unsigned short* d = &Wq[r*72 + c0];
    d[0]=f2us(v.x); d[1]=f2us(v.y); d[2]=f2us(v.z); d[3]=f2us(v.w);
  }
  for (int idx = tid; idx < 1024; idx += 256){       // Wo: 64x64
    int r = idx >> 4, c0 = (idx & 15)*4;
    float4 v = *(const float4*)(Wo + r*64 + c0);
    unsigned short* d = &Wos[r*72 + c0];
    d[0]=f2us(v.x); d[1]=f2us(v.y); d[2]=f2us(v.z); d[3]=f2us(v.w);
  }
  if (tid < 192) bq[tid] = bqkv[tid];
  if (tid < 64){ bos[tid]=bo[tid]; l1w[tid]=ln1w[tid]; l1b[tid]=ln1b[tid]; }
  const int g = blockIdx.x;
  {
    int r = tid >> 2, c0 = (tid & 3)*16;
    int t = r & 3, n = g*16 + (r >> 2);      // row = node_local*4 + t
    const float* src = tokens + (size_t)t*NN*64 + (size_t)n*64 + c0;
    #pragma unroll
    for (int i = 0; i < 4; ++i){
      float4 v = *(const float4*)(src + i*4);
      unsigned short* d = &Xs[r*72 + c0 + i*4];
      d[0]=f2us(v.x); d[1]=f2us(v.y); d[2]=f2us(v.z); d[3]=f2us(v.w);
    }
  }
  __syncthreads();
  const int w = tid >> 6, lane = tid & 63, quad = lane >> 4, c = lane & 15;
  const int rw = w*16;
  bf16x8 a0 = *(const bf16x8*)&Xs[(rw+c)*72 + quad*8];
  bf16x8 a1 = *(const bf16x8*)&Xs[(rw+c)*72 + 32 + quad*8];
  f32x4 qk[12];   // 0-3: q tiles, 4-7: k tiles, 8-11: v tiles
  #pragma unroll
  for (int nt = 0; nt < 12; ++nt){
    f32x4 acc = {0,0,0,0};
    bf16x8 b0 = *(const bf16x8*)&Wq[(nt*16+c)*72 + quad*8];
    bf16x8 b1 = *(const bf16x8*)&Wq[(nt*16+c)*72 + 32 + quad*8];
    acc = __builtin_amdgcn_mfma_f32_16x16x32_bf16(a0, b0, acc, 0,0,0);
    acc = __builtin_amdgcn_mfma_f32_16x16x32_bf16(a1, b1, acc, 0,0,0);
    float bb = bq[nt*16 + c];
    acc[0]+=bb; acc[1]+=bb; acc[2]+=bb; acc[3]+=bb;
    qk[nt] = acc;
  }
  // scores: node = quad (rows quad*4+reg), dims spread over lanes&tiles
  float sc[4][4];
  #pragma unroll
  for (int s = 0; s < 4; ++s){
    #pragma unroll
    for (int t = 0; t < 4; ++t){
      float p = qk[0][s]*qk[4][t] + qk[1][s]*qk[5][t]
              + qk[2][s]*qk[6][t] + qk[3][s]*qk[7][t];
      p += __shfl_xor(p, 1); p += __shfl_xor(p, 2);
      p += __shfl_xor(p, 4); p += __shfl_xor(p, 8);
      sc[s][t] = p * 0.125f;
    }
  }
  float pm[4][4];
  #pragma unroll
  for (int s = 0; s < 4; ++s){
    float m = fmaxf(fmaxf(sc[s][0],sc[s][1]), fmaxf(sc[s][2],sc[s][3]));
    float e0=__expf(sc[s][0]-m), e1=__expf(sc[s][1]-m);
    float e2=__expf(sc[s][2]-m), e3=__expf(sc[s][3]-m);
    float inv = 1.f/(e0+e1+e2+e3);
    pm[s][0]=e0*inv; pm[s][1]=e1*inv; pm[s][2]=e2*inv; pm[s][3]=e3*inv;
  }
  // a = P @ V (local per lane), write to LDS in A-layout
  #pragma unroll
  for (int tile = 0; tile < 4; ++tile){
    #pragma unroll
    for (int s = 0; s < 4; ++s){
      float av = pm[s][0]*qk[8+tile][0] + pm[s][1]*qk[8+tile][1]
               + pm[s][2]*qk[8+tile][2] + pm[s][3]*qk[8+tile][3];
      As2[(rw + quad*4 + s)*72 + tile*16 + c] = f2us(av);
    }
  }
  __syncthreads();
  // out projection
  bf16x8 p0 = *(const bf16x8*)&As2[(rw+c)*72 + quad*8];
  bf16x8 p1 = *(const bf16x8*)&As2[(rw+c)*72 + 32 + quad*8];
  f32x4 ov[4];
  #pragma unroll
  for (int nt = 0; nt < 4; ++nt){
    f32x4 acc = {0,0,0,0};
    bf16x8 b0 = *(const bf16x8*)&Wos[(nt*16+c)*72 + quad*8];
    bf16x8 b1 = *(const bf16x8*)&Wos[(nt*16+c)*72 + 32 + quad*8];
    acc = __builtin_amdgcn_mfma_f32_16x16x32_bf16(p0, b0, acc, 0,0,0);
    acc = __builtin_amdgcn_mfma_f32_16x16x32_bf16(p1, b1, acc, 0,0,0);
    ov[nt] = acc;
  }
  // residual + LN1, store back to tokens
  float r4[4][4];  // [tile][reg]
  #pragma unroll
  for (int nt = 0; nt < 4; ++nt){
    int col = nt*16 + c;
    float bb = bos[col];
    #pragma unroll
    for (int rg = 0; rg < 4; ++rg){
      float seqv = us2f(Xs[(rw + quad*4 + rg)*72 + col]);
      r4[nt][rg] = ov[nt][rg] + bb + seqv;
    }
  }
  #pragma unroll
  for (int rg = 0; rg < 4; ++rg){
    float sm = r4[0][rg]+r4[1][rg]+r4[2][rg]+r4[3][rg];
    sm += __shfl_xor(sm,1); sm += __shfl_xor(sm,2);
    sm += __shfl_xor(sm,4); sm += __shfl_xor(sm,8);
    float mean = sm * (1.f/64.f);
    float d0=r4[0][rg]-mean, d1=r4[1][rg]-mean, d2=r4[2][rg]-mean, d3=r4[3][rg]-mean;
    float vs = d0*d0+d1*d1+d2*d2+d3*d3;
    vs += __shfl_xor(vs,1); vs += __shfl_xor(vs,2);
    vs += __shfl_xor(vs,4); vs += __shfl_xor(vs,8);
    float rinv = rsqrtf(vs*(1.f/64.f) + 1e-5f);
    int row = rw + quad*4 + rg;
    int t = row & 3, n = g*16 + (row >> 2);
    float* dst = tokens + (size_t)t*NN*64 + (size_t)n*64;
    #pragma unroll
    for (int nt = 0; nt < 4; ++nt){
      int col = nt*16 + c;
      dst[col] = (r4[nt][rg] - mean) * rinv * l1w[col] + l1b[col];
    }
  }
}

// ---------------- FFN + LN2 + mean + classifier (MFMA) ----------------
__global__ void __launch_bounds__(256) k_ffn(const float* __restrict__ tokens,
    const float* __restrict__ W1, const float* __restrict__ b1,
    const float* __restrict__ W2, const float* __restrict__ b2,
    const float* __restrict__ ln2w, const float* __restrict__ ln2b,
    const float* __restrict__ Wc, const float* __restrict__ bc,
    float* __restrict__ out){
  __shared__ unsigned short W1s[128*72];
  __shared__ unsigned short W2s[64*136];
  __shared__ unsigned short Wcs[40*72];
  __shared__ unsigned short Xs[64*72];
  __shared__ unsigned short F1[64*136];
  __shared__ float hs[16*68];
  __shared__ float b1s[128], b2s[64], l2w[64], l2b[64], bcs[40];
  const int tid = threadIdx.x;
  for (int idx = tid; idx < 2048; idx += 256){       // W1: 128x64
    int r = idx >> 4, c0 = (idx & 15)*4;
    float4 v = *(const float4*)(W1 + r*64 + c0);
    unsigned short* d = &W1s[r*72 + c0];
    d[0]=f2us(v.x); d[1]=f2us(v.y); d[2]=f2us(v.z); d[3]=f2us(v.w);
  }
  for (int idx = tid; idx < 2048; idx += 256){       // W2: 64x128
    int r = idx >> 5, c0 = (idx & 31)*4;
    float4 v = *(const float4*)(W2 + r*128 + c0);
    unsigned short* d = &W2s[r*136 + c0];
    d[0]=f2us(v.x); d[1]=f2us(v.y); d[2]=f2us(v.z); d[3]=f2us(v.w);
  }
  for (int idx = tid; idx < 640; idx += 256){        // Wc: 40x64
    int r = idx >> 4, c0 = (idx & 15)*4;
    float4 v = *(const float4*)(Wc + r*64 + c0);
    unsigned short* d = &Wcs[r*72 + c0];
    d[0]=f2us(v.x); d[1]=f2us(v.y); d[2]=f2us(v.z); d[3]=f2us(v.w);
  }
  if (tid < 128) b1s[tid] = b1[tid];
  if (tid < 64){ b2s[tid]=b2[tid]; l2w[tid]=ln2w[tid]; l2b[tid]=ln2b[tid]; }
  if (tid < 40)  bcs[tid] = bc[tid];
  const int g = blockIdx.x;
  {
    int r = tid >> 2, c0 = (tid & 3)*16;
    int t = r & 3, n = g*16 + (r >> 2);
    const float* src = tokens + (size_t)t*NN*64 + (size_t)n*64 + c0;
    #pragma unroll
    for (int i = 0; i < 4; ++i){
      float4 v = *(const float4*)(src + i*4);
      unsigned short* d = &Xs[r*72 + c0 + i*4];
      d[0]=f2us(v.x); d[1]=f2us(v.y); d[2]=f2us(v.z); d[3]=f2us(v.w);
    }
  }
  __syncthreads();
  const int w = tid >> 6, lane = tid & 63, quad = lane >> 4, c = lane & 15;
  const int rw = w*16;
  bf16x8 a0 = *(const bf16x8*)&Xs[(rw+c)*72 + quad*8];
  bf16x8 a1 = *(const bf16x8*)&Xs[(rw+c)*72 + 32 + quad*8];
  // ff1 + exact gelu -> F1 (A-layout, bf16)
  #pragma unroll
  for (int nt = 0; nt < 8; ++nt){
    f32x4 acc = {0,0,0,0};
    bf16x8 b0 = *(const bf16x8*)&W1s[(nt*16+c)*72 + quad*8];
    bf16x8 b1v = *(const bf16x8*)&W1s[(nt*16+c)*72 + 32 + quad*8];
    acc = __builtin_amdgcn_mfma_f32_16x16x32_bf16(a0, b0, acc, 0,0,0);
    acc = __builtin_amdgcn_mfma_f32_16x16x32_bf16(a1, b1v, acc, 0,0,0);
    float bb = b1s[nt*16 + c];
    #pragma unroll
    for (int rg = 0; rg < 4; ++rg){
      float v = acc[rg] + bb;
      float ge = 0.5f * v * (1.f + erff(v * 0.70710678118654752f));
      F1[(rw + quad*4 + rg)*136 + nt*16 + c] = f2us(ge);
    }
  }
  __syncthreads();
  // ff2
  bf16x8 fa[4];
  #pragma unroll
  for (int ks = 0; ks < 4; ++ks)
    fa[ks] = *(const bf16x8*)&F1[(rw+c)*136 + ks*32 + quad*8];
  f32x4 ov[4];
  #pragma unroll
  for (int nt = 0; nt < 4; ++nt){
    f32x4 acc = {0,0,0,0};
    #pragma unroll
    for (int ks = 0; ks < 4; ++ks){
      bf16x8 b = *(const bf16x8*)&W2s[(nt*16+c)*136 + ks*32 + quad*8];
      acc = __builtin_amdgcn_mfma_f32_16x16x32_bf16(fa[ks], b, acc, 0,0,0);
    }
    ov[nt] = acc;
  }
  // residual + LN2 + token-mean
  float r4[4][4];
  #pragma unroll
  for (int nt = 0; nt < 4; ++nt){
    int col = nt*16 + c;
    float bb = b2s[col];
    #pragma unroll
    for (int rg = 0; rg < 4; ++rg){
      float seqv = us2f(Xs[(rw + quad*4 + rg)*72 + col]);
      r4[nt][rg] = ov[nt][rg] + bb + seqv;
    }
  }
  float hval[4] = {0.f, 0.f, 0.f, 0.f};
  #pragma unroll
  for (int rg = 0; rg < 4; ++rg){
    float sm = r4[0][rg]+r4[1][rg]+r4[2][rg]+r4[3][rg];
    sm += __shfl_xor(sm,1); sm += __shfl_xor(sm,2);
    sm += __shfl_xor(sm,4); sm += __shfl_xor(sm,8);
    float mean = sm * (1.f/64.f);
    float d0=r4[0][rg]-mean, d1=r4[1][rg]-mean, d2=r4[2][rg]-mean, d3=r4[3][rg]-mean;
    float vs = d0*d0+d1*d1+d2*d2+d3*d3;
    vs += __shfl_xor(vs,1); vs += __shfl_xor(vs,2);
    vs += __shfl_xor(vs,4); vs += __shfl_xor(vs,8);
    float rinv = rsqrtf(vs*(1.f/64.f) + 1e-5f);
    #pragma unroll
    for (int nt = 0; nt < 4; ++nt){
      int col = nt*16 + c;
      hval[nt] += (r4[nt][rg] - mean) * rinv * l2w[col] + l2b[col];
    }
  }
  #pragma unroll
  for (int nt = 0; nt < 4; ++nt)
    hs[(w*4 + quad)*68 + nt*16 + c] = hval[nt] * 0.25f;
  __syncthreads();
  // classifier: 16 nodes x 40 outs
  for (int p = tid; p < 16*OUTC; p += 256){
    int node = p / OUTC, o = p - node*OUTC;
    float acc = bcs[o];
    const unsigned* wrow = (const unsigned*)&Wcs[o*72];
    const float2*  hrow = (const float2*)&hs[node*68];
    #pragma unroll 8
    for (int j2 = 0; j2 < 32; ++j2){
      unsigned u = wrow[j2];
      float2 hv = hrow[j2];
      acc += hv.x*lo_f(u) + hv.y*hi_f(u);
    }
    out[(size_t)(g*16 + node)*OUTC + o] = acc;
  }
}

extern "C" void kernel_launch(void* const* d_in, const int* in_sizes, int n_in,
                              void* d_out, int out_size, void* d_ws, size_t ws_size,
                              hipStream_t stream) {
  const float* x    = (const float*)d_in[0];
  const int*   ei   = (const int*  )d_in[1];
  const float* Win  = (const float*)d_in[2];
  const float* bin  = (const float*)d_in[3];
  const float* sgW  = (const float*)d_in[4];
  const float* sgb  = (const float*)d_in[5];
  const float* Wqkv = (const float*)d_in[6];
  const float* bqkv = (const float*)d_in[7];
  const float* Wo   = (const float*)d_in[8];
  const float* bo   = (const float*)d_in[9];
  const float* W1   = (const float*)d_in[10];
  const float* b1   = (const float*)d_in[11];
  const float* W2   = (const float*)d_in[12];
  const float* b2   = (const float*)d_in[13];
  const float* ln1w = (const float*)d_in[14];
  const float* ln1b = (const float*)d_in[15];
  const float* ln2w = (const float*)d_in[16];
  const float* ln2b = (const float*)d_in[17];
  const float* Wc   = (const float*)d_in[18];
  const float* bc   = (const float*)d_in[19];

  char* ws = (char*)d_ws;
  float* deg    = (float*)(ws);                    // 400,000 B
  float* nrm    = (float*)(ws + 400128);           // 6,400,000 B
  float* tokens = (float*)(ws + 6800128);          // 4*N*64*4 = 102,400,000 B
  float* pbuf0  = (float*)(ws + 109200128);        // 25,600,000 B
  float* pbuf1  = (float*)(ws + 134800128);        // 25,600,000 B

  k_deg_init<<<(NN+255)/256, 256, 0, stream>>>(deg);
  k_deg_count<<<(EE+255)/256, 256, 0, stream>>>(ei, deg);
  k_dinv<<<(NN+255)/256, 256, 0, stream>>>(deg);
  k_norm<<<(EE+255)/256, 256, 0, stream>>>(ei, deg, nrm);

  const int GB = (NN + 63) / 64;                   // 1563
  k_h0<<<GB, 256, 0, stream>>>(x, Win, bin, deg, tokens, pbuf0);

  // hop 1: cur1 = pbuf0 (init by k_h0); prev = tokens[0]
  k_scatter<<<8192, 256, 0, stream>>>(ei, nrm, tokens, pbuf0);
  k_token<<<GB, 256, 0, stream>>>(pbuf0, sgW, sgb, deg,
                                  tokens + (size_t)1*NN*64, pbuf1);   // init cur2
  // hop 2
  k_scatter<<<8192, 256, 0, stream>>>(ei, nrm, pbuf0, pbuf1);
  k_token<<<GB, 256, 0, stream>>>(pbuf1, sgW + 4096, sgb + 64, deg,
                                  tokens + (size_t)2*NN*64, pbuf0);   // init cur3
  // hop 3
  k_scatter<<<8192, 256, 0, stream>>>(ei, nrm, pbuf1, pbuf0);
  k_token<<<GB, 256, 0, stream>>>(pbuf0, sgW + 8192, sgb + 128, deg,
                                  tokens + (size_t)3*NN*64, nullptr);

  k_attn<<<NN/16, 256, 0, stream>>>(tokens, Wqkv, bqkv, Wo, bo, ln1w, ln1b);
  k_ffn<<<NN/16, 256, 0, stream>>>(tokens, W1, b1, W2, b2, ln2w, ln2b, Wc, bc,
                                   (float*)d_out);
}

// Round 4
// 1196.632 us; speedup vs baseline: 2.6258x; 1.3732x over previous
//
#include <hip/hip_runtime.h>
#include <hip/hip_bf16.h>
#include <math.h>

#define NN 100000
#define EE 1600000
#define OUTC 40

typedef __hip_bfloat16 bf16;
typedef __attribute__((ext_vector_type(8))) short bf16x8;
typedef __attribute__((ext_vector_type(4))) float f32x4;

__device__ __forceinline__ unsigned short f2us(float f){
  bf16 b = __float2bfloat16(f);
  unsigned short u; __builtin_memcpy(&u, &b, 2); return u;
}
__device__ __forceinline__ float us2f(unsigned short u){
  union{unsigned x; float f;} c; c.x = ((unsigned)u)<<16; return c.f;
}
__device__ __forceinline__ float lo_f(unsigned u){ union{unsigned x;float f;}c; c.x = u<<16; return c.f; }
__device__ __forceinline__ float hi_f(unsigned u){ union{unsigned x;float f;}c; c.x = u & 0xffff0000u; return c.f; }

// ---------------- CSR build ----------------
__global__ void k_zero(int* cnt){
  int i = blockIdx.x*blockDim.x + threadIdx.x;
  if (i < NN) cnt[i] = 0;
}
__global__ void k_cnt(const int* __restrict__ ei, int* cnt){
  int e = blockIdx.x*blockDim.x + threadIdx.x;
  if (e < EE) atomicAdd(&cnt[ei[EE + e]], 1);
}
// in-place: fill[] holds counts on entry, exclusive prefix on exit; dinv = rsqrt(cnt+1)
__global__ void __launch_bounds__(1024) k_scan(int* fill, float* dinv){
  __shared__ int tot[1024];
  const int t = threadIdx.x;
  const int lo = t*98;
  const int hi = min(lo + 98, NN);
  int s = 0;
  for (int i = lo; i < hi; ++i) s += fill[i];
  tot[t] = s;
  __syncthreads();
  for (int st = 1; st < 1024; st <<= 1){
    int v = tot[t];
    int add = (t >= st) ? tot[t - st] : 0;
    __syncthreads();
    tot[t] = v + add;
    __syncthreads();
  }
  int run = (t > 0) ? tot[t-1] : 0;
  for (int i = lo; i < hi; ++i){
    int c = fill[i];
    fill[i] = run;
    dinv[i] = rsqrtf((float)c + 1.0f);
    run += c;
  }
}
// bump-fill: after this, fill[n] = end of node n's segment (inclusive prefix)
__global__ void k_fill(const int* __restrict__ ei, int* fill, int* csr_src){
  int e = blockIdx.x*blockDim.x + threadIdx.x;
  if (e < EE){
    int d = ei[EE + e];
    int p = atomicAdd(&fill[d], 1);
    csr_src[p] = ei[e];
  }
}

// ---------------- gather propagation: cur = S @ prev (no atomics) ----------------
__global__ void __launch_bounds__(256) k_gather(const int* __restrict__ fill,
    const int* __restrict__ csr_src, const float* __restrict__ dinv,
    const float* __restrict__ prev, float* __restrict__ cur){
  int wid = (blockIdx.x*256 + threadIdx.x) >> 6;
  int lane = threadIdx.x & 63;
  if (wid >= NN) return;
  const int n = wid;
  int b = (n == 0) ? 0 : fill[n-1];
  int e = fill[n];
  float dn = dinv[n];
  float acc = prev[(size_t)n*64 + lane] * dn * dn;
  for (int base = b; base < e; base += 64){
    int idx = base + lane;
    int sv = 0; float wv = 0.f;
    if (idx < e){ sv = csr_src[idx]; wv = dinv[sv] * dn; }
    int m = min(64, e - base);
    for (int j = 0; j < m; ++j){
      int s = __shfl(sv, j);
      float w = __shfl(wv, j);
      acc += prev[(size_t)s*64 + lane] * w;
    }
  }
  cur[(size_t)n*64 + lane] = acc;
}

// ---------------- h0 = relu(x @ W_in^T + b_in) ----------------
__global__ void __launch_bounds__(256) k_h0(const float* __restrict__ x,
    const float* __restrict__ Win, const float* __restrict__ bin,
    float* __restrict__ tok0){
  __shared__ unsigned short Xs[64*264];
  __shared__ unsigned short Ws[64*264];
  __shared__ float bs[64];
  const int tid = threadIdx.x;
  for (int idx = tid; idx < 4096; idx += 256){       // Win: 64x256
    int r = idx >> 6, c0 = (idx & 63) * 4;
    float4 v = *(const float4*)(Win + r*256 + c0);
    unsigned short* d = &Ws[r*264 + c0];
    d[0]=f2us(v.x); d[1]=f2us(v.y); d[2]=f2us(v.z); d[3]=f2us(v.w);
  }
  const int n0 = blockIdx.x * 64;
  for (int idx = tid; idx < 4096; idx += 256){       // X tile: 64x256
    int r = idx >> 6, c0 = (idx & 63) * 4;
    int n = n0 + r; if (n >= NN) n = NN-1;
    float4 v = *(const float4*)(x + (size_t)n*256 + c0);
    unsigned short* d = &Xs[r*264 + c0];
    d[0]=f2us(v.x); d[1]=f2us(v.y); d[2]=f2us(v.z); d[3]=f2us(v.w);
  }
  if (tid < 64) bs[tid] = bin[tid];
  __syncthreads();
  const int w = tid >> 6, lane = tid & 63, quad = lane >> 4, c = lane & 15;
  f32x4 acc[4] = {{0,0,0,0},{0,0,0,0},{0,0,0,0},{0,0,0,0}};
  #pragma unroll
  for (int ks = 0; ks < 8; ++ks){
    int k0 = ks*32 + quad*8;
    bf16x8 a = *(const bf16x8*)&Xs[(w*16 + c)*264 + k0];
    #pragma unroll
    for (int nt = 0; nt < 4; ++nt){
      bf16x8 b = *(const bf16x8*)&Ws[(nt*16 + c)*264 + k0];
      acc[nt] = __builtin_amdgcn_mfma_f32_16x16x32_bf16(a, b, acc[nt], 0,0,0);
    }
  }
  #pragma unroll
  for (int nt = 0; nt < 4; ++nt){
    int col = nt*16 + c;
    float bb = bs[col];
    #pragma unroll
    for (int rg = 0; rg < 4; ++rg){
      int n = n0 + w*16 + quad*4 + rg;
      if (n < NN) tok0[(size_t)n*64 + col] = fmaxf(acc[nt][rg] + bb, 0.f);
    }
  }
}

// ------- token = relu(cur @ sgW^T + sgb) -------
__global__ void __launch_bounds__(256) k_token(const float* __restrict__ cur,
    const float* __restrict__ sgW, const float* __restrict__ sgb,
    float* __restrict__ tok){
  __shared__ unsigned short Xs[64*72];
  __shared__ unsigned short Ws[64*72];
  __shared__ float bs[64];
  const int tid = threadIdx.x;
  for (int idx = tid; idx < 1024; idx += 256){       // sgW: 64x64
    int r = idx >> 4, c0 = (idx & 15)*4;
    float4 v = *(const float4*)(sgW + r*64 + c0);
    unsigned short* d = &Ws[r*72 + c0];
    d[0]=f2us(v.x); d[1]=f2us(v.y); d[2]=f2us(v.z); d[3]=f2us(v.w);
  }
  if (tid < 64) bs[tid] = sgb[tid];
  const int n0 = blockIdx.x*64;
  {
    int r = tid >> 2, c0 = (tid & 3)*16;
    int n = n0 + r; if (n >= NN) n = NN-1;
    #pragma unroll
    for (int i = 0; i < 4; ++i){
      float4 v = *(const float4*)(cur + (size_t)n*64 + c0 + i*4);
      unsigned short* d = &Xs[r*72 + c0 + i*4];
      d[0]=f2us(v.x); d[1]=f2us(v.y); d[2]=f2us(v.z); d[3]=f2us(v.w);
    }
  }
  __syncthreads();
  const int w = tid >> 6, lane = tid & 63, quad = lane >> 4, c = lane & 15;
  f32x4 acc[4] = {{0,0,0,0},{0,0,0,0},{0,0,0,0},{0,0,0,0}};
  #pragma unroll
  for (int ks = 0; ks < 2; ++ks){
    int k0 = ks*32 + quad*8;
    bf16x8 a = *(const bf16x8*)&Xs[(w*16 + c)*72 + k0];
    #pragma unroll
    for (int nt = 0; nt < 4; ++nt){
      bf16x8 b = *(const bf16x8*)&Ws[(nt*16 + c)*72 + k0];
      acc[nt] = __builtin_amdgcn_mfma_f32_16x16x32_bf16(a, b, acc[nt], 0,0,0);
    }
  }
  #pragma unroll
  for (int nt = 0; nt < 4; ++nt){
    int col = nt*16 + c;
    float bb = bs[col];
    #pragma unroll
    for (int rg = 0; rg < 4; ++rg){
      int n = n0 + w*16 + quad*4 + rg;
      if (n < NN) tok[(size_t)n*64 + col] = fmaxf(acc[nt][rg] + bb, 0.f);
    }
  }
}

// ---------------- attention + LN1 (MFMA, in-place on tokens) ----------------
__global__ void __launch_bounds__(256) k_attn(float* __restrict__ tokens,
    const float* __restrict__ Wqkv, const float* __restrict__ bqkv,
    const float* __restrict__ Wo,   const float* __restrict__ bo,
    const float* __restrict__ ln1w, const float* __restrict__ ln1b){
  __shared__ unsigned short Wq[192*72];
  __shared__ unsigned short Wos[64*72];
  __shared__ unsigned short Xs[64*72];
  __shared__ unsigned short As2[64*72];
  __shared__ float bq[192], bos[64], l1w[64], l1b[64];
  const int tid = threadIdx.x;
  for (int idx = tid; idx < 3072; idx += 256){       // Wqkv: 192x64
    int r = idx >> 4, c0 = (idx & 15)*4;
    float4 v = *(const float4*)(Wqkv + r*64 + c0);
    unsigned short* d = &Wq[r*72 + c0];
    d[0]=f2us(v.x); d[1]=f2us(v.y); d[2]=f2us(v.z); d[3]=f2us(v.w);
  }
  for (int idx = tid; idx < 1024; idx += 256){       // Wo: 64x64
    int r = idx >> 4, c0 = (idx & 15)*4;
    float4 v = *(const float4*)(Wo + r*64 + c0);
    unsigned short* d = &Wos[r*72 + c0];
    d[0]=f2us(v.x); d[1]=f2us(v.y); d[2]=f2us(v.z); d[3]=f2us(v.w);
  }
  if (tid < 192) bq[tid] = bqkv[tid];
  if (tid < 64){ bos[tid]=bo[tid]; l1w[tid]=ln1w[tid]; l1b[tid]=ln1b[tid]; }
  const int g = blockIdx.x;
  {
    int r = tid >> 2, c0 = (tid & 3)*16;
    int t = r & 3, n = g*16 + (r >> 2);      // row = node_local*4 + t
    const float* src = tokens + (size_t)t*NN*64 + (size_t)n*64 + c0;
    #pragma unroll
    for (int i = 0; i < 4; ++i){
      float4 v = *(const float4*)(src + i*4);
      unsigned short* d = &Xs[r*72 + c0 + i*4];
      d[0]=f2us(v.x); d[1]=f2us(v.y); d[2]=f2us(v.z); d[3]=f2us(v.w);
    }
  }
  __syncthreads();
  const int w = tid >> 6, lane = tid & 63, quad = lane >> 4, c = lane & 15;
  const int rw = w*16;
  bf16x8 a0 = *(const bf16x8*)&Xs[(rw+c)*72 + quad*8];
  bf16x8 a1 = *(const bf16x8*)&Xs[(rw+c)*72 + 32 + quad*8];
  f32x4 qk[12];   // 0-3: q tiles, 4-7: k tiles, 8-11: v tiles
  #pragma unroll
  for (int nt = 0; nt < 12; ++nt){
    f32x4 acc = {0,0,0,0};
    bf16x8 b0 = *(const bf16x8*)&Wq[(nt*16+c)*72 + quad*8];
    bf16x8 b1 = *(const bf16x8*)&Wq[(nt*16+c)*72 + 32 + quad*8];
    acc = __builtin_amdgcn_mfma_f32_16x16x32_bf16(a0, b0, acc, 0,0,0);
    acc = __builtin_amdgcn_mfma_f32_16x16x32_bf16(a1, b1, acc, 0,0,0);
    float bb = bq[nt*16 + c];
    acc[0]+=bb; acc[1]+=bb; acc[2]+=bb; acc[3]+=bb;
    qk[nt] = acc;
  }
  // scores: node = quad (rows quad*4+reg), dims spread over lanes&tiles
  float sc[4][4];
  #pragma unroll
  for (int s = 0; s < 4; ++s){
    #pragma unroll
    for (int t = 0; t < 4; ++t){
      float p = qk[0][s]*qk[4][t] + qk[1][s]*qk[5][t]
              + qk[2][s]*qk[6][t] + qk[3][s]*qk[7][t];
      p += __shfl_xor(p, 1); p += __shfl_xor(p, 2);
      p += __shfl_xor(p, 4); p += __shfl_xor(p, 8);
      sc[s][t] = p * 0.125f;
    }
  }
  float pm[4][4];
  #pragma unroll
  for (int s = 0; s < 4; ++s){
    float m = fmaxf(fmaxf(sc[s][0],sc[s][1]), fmaxf(sc[s][2],sc[s][3]));
    float e0=__expf(sc[s][0]-m), e1=__expf(sc[s][1]-m);
    float e2=__expf(sc[s][2]-m), e3=__expf(sc[s][3]-m);
    float inv = 1.f/(e0+e1+e2+e3);
    pm[s][0]=e0*inv; pm[s][1]=e1*inv; pm[s][2]=e2*inv; pm[s][3]=e3*inv;
  }
  // a = P @ V (local per lane), write to LDS in A-layout
  #pragma unroll
  for (int tile = 0; tile < 4; ++tile){
    #pragma unroll
    for (int s = 0; s < 4; ++s){
      float av = pm[s][0]*qk[8+tile][0] + pm[s][1]*qk[8+tile][1]
               + pm[s][2]*qk[8+tile][2] + pm[s][3]*qk[8+tile][3];
      As2[(rw + quad*4 + s)*72 + tile*16 + c] = f2us(av);
    }
  }
  __syncthreads();
  // out projection
  bf16x8 p0 = *(const bf16x8*)&As2[(rw+c)*72 + quad*8];
  bf16x8 p1 = *(const bf16x8*)&As2[(rw+c)*72 + 32 + quad*8];
  f32x4 ov[4];
  #pragma unroll
  for (int nt = 0; nt < 4; ++nt){
    f32x4 acc = {0,0,0,0};
    bf16x8 b0 = *(const bf16x8*)&Wos[(nt*16+c)*72 + quad*8];
    bf16x8 b1 = *(const bf16x8*)&Wos[(nt*16+c)*72 + 32 + quad*8];
    acc = __builtin_amdgcn_mfma_f32_16x16x32_bf16(p0, b0, acc, 0,0,0);
    acc = __builtin_amdgcn_mfma_f32_16x16x32_bf16(p1, b1, acc, 0,0,0);
    ov[nt] = acc;
  }
  // residual + LN1, store back to tokens
  float r4[4][4];  // [tile][reg]
  #pragma unroll
  for (int nt = 0; nt < 4; ++nt){
    int col = nt*16 + c;
    float bb = bos[col];
    #pragma unroll
    for (int rg = 0; rg < 4; ++rg){
      float seqv = us2f(Xs[(rw + quad*4 + rg)*72 + col]);
      r4[nt][rg] = ov[nt][rg] + bb + seqv;
    }
  }
  #pragma unroll
  for (int rg = 0; rg < 4; ++rg){
    float sm = r4[0][rg]+r4[1][rg]+r4[2][rg]+r4[3][rg];
    sm += __shfl_xor(sm,1); sm += __shfl_xor(sm,2);
    sm += __shfl_xor(sm,4); sm += __shfl_xor(sm,8);
    float mean = sm * (1.f/64.f);
    float d0=r4[0][rg]-mean, d1=r4[1][rg]-mean, d2=r4[2][rg]-mean, d3=r4[3][rg]-mean;
    float vs = d0*d0+d1*d1+d2*d2+d3*d3;
    vs += __shfl_xor(vs,1); vs += __shfl_xor(vs,2);
    vs += __shfl_xor(vs,4); vs += __shfl_xor(vs,8);
    float rinv = rsqrtf(vs*(1.f/64.f) + 1e-5f);
    int row = rw + quad*4 + rg;
    int t = row & 3, n = g*16 + (row >> 2);
    float* dst = tokens + (size_t)t*NN*64 + (size_t)n*64;
    #pragma unroll
    for (int nt = 0; nt < 4; ++nt){
      int col = nt*16 + c;
      dst[col] = (r4[nt][rg] - mean) * rinv * l1w[col] + l1b[col];
    }
  }
}

// ---------------- FFN + LN2 + mean + classifier (MFMA) ----------------
__global__ void __launch_bounds__(256) k_ffn(const float* __restrict__ tokens,
    const float* __restrict__ W1, const float* __restrict__ b1,
    const float* __restrict__ W2, const float* __restrict__ b2,
    const float* __restrict__ ln2w, const float* __restrict__ ln2b,
    const float* __restrict__ Wc, const float* __restrict__ bc,
    float* __restrict__ out){
  __shared__ unsigned short W1s[128*72];
  __shared__ unsigned short W2s[64*136];
  __shared__ unsigned short Wcs[40*72];
  __shared__ unsigned short Xs[64*72];
  __shared__ unsigned short F1[64*136];
  __shared__ float hs[16*68];
  __shared__ float b1s[128], b2s[64], l2w[64], l2b[64], bcs[40];
  const int tid = threadIdx.x;
  for (int idx = tid; idx < 2048; idx += 256){       // W1: 128x64
    int r = idx >> 4, c0 = (idx & 15)*4;
    float4 v = *(const float4*)(W1 + r*64 + c0);
    unsigned short* d = &W1s[r*72 + c0];
    d[0]=f2us(v.x); d[1]=f2us(v.y); d[2]=f2us(v.z); d[3]=f2us(v.w);
  }
  for (int idx = tid; idx < 2048; idx += 256){       // W2: 64x128
    int r = idx >> 5, c0 = (idx & 31)*4;
    float4 v = *(const float4*)(W2 + r*128 + c0);
    unsigned short* d = &W2s[r*136 + c0];
    d[0]=f2us(v.x); d[1]=f2us(v.y); d[2]=f2us(v.z); d[3]=f2us(v.w);
  }
  for (int idx = tid; idx < 640; idx += 256){        // Wc: 40x64
    int r = idx >> 4, c0 = (idx & 15)*4;
    float4 v = *(const float4*)(Wc + r*64 + c0);
    unsigned short* d = &Wcs[r*72 + c0];
    d[0]=f2us(v.x); d[1]=f2us(v.y); d[2]=f2us(v.z); d[3]=f2us(v.w);
  }
  if (tid < 128) b1s[tid] = b1[tid];
  if (tid < 64){ b2s[tid]=b2[tid]; l2w[tid]=ln2w[tid]; l2b[tid]=ln2b[tid]; }
  if (tid < 40)  bcs[tid] = bc[tid];
  const int g = blockIdx.x;
  {
    int r = tid >> 2, c0 = (tid & 3)*16;
    int t = r & 3, n = g*16 + (r >> 2);
    const float* src = tokens + (size_t)t*NN*64 + (size_t)n*64 + c0;
    #pragma unroll
    for (int i = 0; i < 4; ++i){
      float4 v = *(const float4*)(src + i*4);
      unsigned short* d = &Xs[r*72 + c0 + i*4];
      d[0]=f2us(v.x); d[1]=f2us(v.y); d[2]=f2us(v.z); d[3]=f2us(v.w);
    }
  }
  __syncthreads();
  const int w = tid >> 6, lane = tid & 63, quad = lane >> 4, c = lane & 15;
  const int rw = w*16;
  bf16x8 a0 = *(const bf16x8*)&Xs[(rw+c)*72 + quad*8];
  bf16x8 a1 = *(const bf16x8*)&Xs[(rw+c)*72 + 32 + quad*8];
  // ff1 + exact gelu -> F1 (A-layout, bf16)
  #pragma unroll
  for (int nt = 0; nt < 8; ++nt){
    f32x4 acc = {0,0,0,0};
    bf16x8 b0 = *(const bf16x8*)&W1s[(nt*16+c)*72 + quad*8];
    bf16x8 b1v = *(const bf16x8*)&W1s[(nt*16+c)*72 + 32 + quad*8];
    acc = __builtin_amdgcn_mfma_f32_16x16x32_bf16(a0, b0, acc, 0,0,0);
    acc = __builtin_amdgcn_mfma_f32_16x16x32_bf16(a1, b1v, acc, 0,0,0);
    float bb = b1s[nt*16 + c];
    #pragma unroll
    for (int rg = 0; rg < 4; ++rg){
      float v = acc[rg] + bb;
      float ge = 0.5f * v * (1.f + erff(v * 0.70710678118654752f));
      F1[(rw + quad*4 + rg)*136 + nt*16 + c] = f2us(ge);
    }
  }
  __syncthreads();
  // ff2
  bf16x8 fa[4];
  #pragma unroll
  for (int ks = 0; ks < 4; ++ks)
    fa[ks] = *(const bf16x8*)&F1[(rw+c)*136 + ks*32 + quad*8];
  f32x4 ov[4];
  #pragma unroll
  for (int nt = 0; nt < 4; ++nt){
    f32x4 acc = {0,0,0,0};
    #pragma unroll
    for (int ks = 0; ks < 4; ++ks){
      bf16x8 b = *(const bf16x8*)&W2s[(nt*16+c)*136 + ks*32 + quad*8];
      acc = __builtin_amdgcn_mfma_f32_16x16x32_bf16(fa[ks], b, acc, 0,0,0);
    }
    ov[nt] = acc;
  }
  // residual + LN2 + token-mean
  float r4[4][4];
  #pragma unroll
  for (int nt = 0; nt < 4; ++nt){
    int col = nt*16 + c;
    float bb = b2s[col];
    #pragma unroll
    for (int rg = 0; rg < 4; ++rg){
      float seqv = us2f(Xs[(rw + quad*4 + rg)*72 + col]);
      r4[nt][rg] = ov[nt][rg] + bb + seqv;
    }
  }
  float hval[4] = {0.f, 0.f, 0.f, 0.f};
  #pragma unroll
  for (int rg = 0; rg < 4; ++rg){
    float sm = r4[0][rg]+r4[1][rg]+r4[2][rg]+r4[3][rg];
    sm += __shfl_xor(sm,1); sm += __shfl_xor(sm,2);
    sm += __shfl_xor(sm,4); sm += __shfl_xor(sm,8);
    float mean = sm * (1.f/64.f);
    float d0=r4[0][rg]-mean, d1=r4[1][rg]-mean, d2=r4[2][rg]-mean, d3=r4[3][rg]-mean;
    float vs = d0*d0+d1*d1+d2*d2+d3*d3;
    vs += __shfl_xor(vs,1); vs += __shfl_xor(vs,2);
    vs += __shfl_xor(vs,4); vs += __shfl_xor(vs,8);
    float rinv = rsqrtf(vs*(1.f/64.f) + 1e-5f);
    #pragma unroll
    for (int nt = 0; nt < 4; ++nt){
      int col = nt*16 + c;
      hval[nt] += (r4[nt][rg] - mean) * rinv * l2w[col] + l2b[col];
    }
  }
  #pragma unroll
  for (int nt = 0; nt < 4; ++nt)
    hs[(w*4 + quad)*68 + nt*16 + c] = hval[nt] * 0.25f;
  __syncthreads();
  // classifier: 16 nodes x 40 outs
  for (int p = tid; p < 16*OUTC; p += 256){
    int node = p / OUTC, o = p - node*OUTC;
    float acc = bcs[o];
    const unsigned* wrow = (const unsigned*)&Wcs[o*72];
    const float2*  hrow = (const float2*)&hs[node*68];
    #pragma unroll 8
    for (int j2 = 0; j2 < 32; ++j2){
      unsigned u = wrow[j2];
      float2 hv = hrow[j2];
      acc += hv.x*lo_f(u) + hv.y*hi_f(u);
    }
    out[(size_t)(g*16 + node)*OUTC + o] = acc;
  }
}

extern "C" void kernel_launch(void* const* d_in, const int* in_sizes, int n_in,
                              void* d_out, int out_size, void* d_ws, size_t ws_size,
                              hipStream_t stream) {
  const float* x    = (const float*)d_in[0];
  const int*   ei   = (const int*  )d_in[1];
  const float* Win  = (const float*)d_in[2];
  const float* bin  = (const float*)d_in[3];
  const float* sgW  = (const float*)d_in[4];
  const float* sgb  = (const float*)d_in[5];
  const float* Wqkv = (const float*)d_in[6];
  const float* bqkv = (const float*)d_in[7];
  const float* Wo   = (const float*)d_in[8];
  const float* bo   = (const float*)d_in[9];
  const float* W1   = (const float*)d_in[10];
  const float* b1   = (const float*)d_in[11];
  const float* W2   = (const float*)d_in[12];
  const float* b2   = (const float*)d_in[13];
  const float* ln1w = (const float*)d_in[14];
  const float* ln1b = (const float*)d_in[15];
  const float* ln2w = (const float*)d_in[16];
  const float* ln2b = (const float*)d_in[17];
  const float* Wc   = (const float*)d_in[18];
  const float* bc   = (const float*)d_in[19];

  char* ws = (char*)d_ws;
  float* dinv   = (float*)(ws);                    // 400,000 B
  int*   fill   = (int*  )(ws + 400128);           // 400,000 B (counts -> prefix -> bump)
  float* tokens = (float*)(ws + 800256);           // 4*N*64*4 = 102,400,000 B
  float* pbuf0  = (float*)(ws + 103200256);        // 25,600,000 B
  float* pbuf1  = (float*)(ws + 128800256);        // 25,600,000 B
  // csr_src aliases the (not-yet-written) hop-3 token slot: 6.4 MB inside 25.6 MB
  int*   csr_src = (int*)(tokens + (size_t)3*NN*64);

  // --- CSR build (once; reused by all 3 hops) ---
  k_zero<<<(NN+255)/256, 256, 0, stream>>>(fill);
  k_cnt <<<(EE+255)/256, 256, 0, stream>>>(ei, fill);
  k_scan<<<1, 1024, 0, stream>>>(fill, dinv);
  k_fill<<<(EE+255)/256, 256, 0, stream>>>(ei, fill, csr_src);

  const int GB = (NN + 63) / 64;                   // 1563
  const int GG = (NN*64 + 255) / 256;              // 25000 (wave per node)
  k_h0<<<GB, 256, 0, stream>>>(x, Win, bin, tokens);

  // hop 1
  k_gather<<<GG, 256, 0, stream>>>(fill, csr_src, dinv, tokens, pbuf0);
  k_token <<<GB, 256, 0, stream>>>(pbuf0, sgW, sgb, tokens + (size_t)1*NN*64);
  // hop 2
  k_gather<<<GG, 256, 0, stream>>>(fill, csr_src, dinv, pbuf0, pbuf1);
  k_token <<<GB, 256, 0, stream>>>(pbuf1, sgW + 4096, sgb + 64, tokens + (size_t)2*NN*64);
  // hop 3
  k_gather<<<GG, 256, 0, stream>>>(fill, csr_src, dinv, pbuf1, pbuf0);
  k_token <<<GB, 256, 0, stream>>>(pbuf0, sgW + 8192, sgb + 128, tokens + (size_t)3*NN*64);

  k_attn<<<NN/16, 256, 0, stream>>>(tokens, Wqkv, bqkv, Wo, bo, ln1w, ln1b);
  k_ffn<<<NN/16, 256, 0, stream>>>(tokens, W1, b1, W2, b2, ln2w, ln2b, Wc, bc,
                                   (float*)d_out);
}

// Round 5
// 994.084 us; speedup vs baseline: 3.1608x; 1.2038x over previous
//
#include <hip/hip_runtime.h>
#include <hip/hip_bf16.h>
#include <math.h>

#define NN 100000
#define EE 1600000
#define OUTC 40
#define NB 391            // (NN+255)/256

typedef __hip_bfloat16 bf16;
typedef __attribute__((ext_vector_type(8))) short bf16x8;
typedef __attribute__((ext_vector_type(4))) float f32x4;

__device__ __forceinline__ unsigned short f2us(float f){
  bf16 b = __float2bfloat16(f);
  unsigned short u; __builtin_memcpy(&u, &b, 2); return u;
}
__device__ __forceinline__ float us2f(unsigned short u){
  union{unsigned x; float f;} c; c.x = ((unsigned)u)<<16; return c.f;
}
__device__ __forceinline__ float lo_f(unsigned u){ union{unsigned x;float f;}c; c.x = u<<16; return c.f; }
__device__ __forceinline__ float hi_f(unsigned u){ union{unsigned x;float f;}c; c.x = u & 0xffff0000u; return c.f; }

// ---------------- CSR build ----------------
__global__ void k_zero(int* cnt){
  int i = blockIdx.x*blockDim.x + threadIdx.x;
  if (i < NN) cnt[i] = 0;
}
__global__ void k_cnt(const int* __restrict__ ei, int* cnt){
  int e = blockIdx.x*blockDim.x + threadIdx.x;
  if (e < EE) atomicAdd(&cnt[ei[EE + e]], 1);
}
// stage 1: per-block (256-wide) sums of cnt
__global__ void __launch_bounds__(256) k_bsum(const int* __restrict__ cnt, int* __restrict__ bsum){
  __shared__ int wsum[4];
  int i = blockIdx.x*256 + threadIdx.x;
  int v = (i < NN) ? cnt[i] : 0;
  #pragma unroll
  for (int m = 1; m < 64; m <<= 1) v += __shfl_xor(v, m);
  if ((threadIdx.x & 63) == 0) wsum[threadIdx.x >> 6] = v;
  __syncthreads();
  if (threadIdx.x == 0) bsum[blockIdx.x] = wsum[0] + wsum[1] + wsum[2] + wsum[3];
}
// stage 2: exclusive scan of NB block sums, in place (single block)
__global__ void __launch_bounds__(512) k_scanb(int* bsum){
  __shared__ int sh[512];
  const int t = threadIdx.x;
  int v = (t < NB) ? bsum[t] : 0;
  sh[t] = v;
  __syncthreads();
  int acc = v;
  for (int st = 1; st < 512; st <<= 1){
    int add = (t >= st) ? sh[t - st] : 0;
    __syncthreads();
    acc += add; sh[t] = acc;
    __syncthreads();
  }
  if (t < NB) bsum[t] = acc - v;   // exclusive
}
// stage 3: in-block exclusive scan + block offset -> fill; dinv from counts
__global__ void __launch_bounds__(256) k_scan2(const int* __restrict__ cnt,
    const int* __restrict__ bsum, int* __restrict__ fill, float* __restrict__ dinv){
  __shared__ int sh[256];
  const int t = threadIdx.x;
  int i = blockIdx.x*256 + t;
  int c = (i < NN) ? cnt[i] : 0;
  sh[t] = c;
  __syncthreads();
  int acc = c;
  for (int st = 1; st < 256; st <<= 1){
    int add = (t >= st) ? sh[t - st] : 0;
    __syncthreads();
    acc += add; sh[t] = acc;
    __syncthreads();
  }
  if (i < NN){
    fill[i] = bsum[blockIdx.x] + acc - c;      // exclusive prefix
    dinv[i] = rsqrtf((float)c + 1.0f);
  }
}
// bump-fill: after this, fill[n] = end of node n's segment
__global__ void k_fill(const int* __restrict__ ei, int* fill, int* csr_src){
  int e = blockIdx.x*blockDim.x + threadIdx.x;
  if (e < EE){
    int d = ei[EE + e];
    int p = atomicAdd(&fill[d], 1);
    csr_src[p] = ei[e];
  }
}

// ---------------- gather propagation: cur = S @ prev (no atomics) ----------------
__global__ void __launch_bounds__(256) k_gather(const int* __restrict__ fill,
    const int* __restrict__ csr_src, const float* __restrict__ dinv,
    const float* __restrict__ prev, float* __restrict__ cur){
  int wid = (blockIdx.x*256 + threadIdx.x) >> 6;
  int lane = threadIdx.x & 63;
  if (wid >= NN) return;
  const int n = wid;
  int b = (n == 0) ? 0 : fill[n-1];
  int e = fill[n];
  float dn = dinv[n];
  float acc = prev[(size_t)n*64 + lane] * dn * dn;
  for (int base = b; base < e; base += 64){
    int idx = base + lane;
    int sv = 0; float wv = 0.f;
    if (idx < e){ sv = csr_src[idx]; wv = dinv[sv] * dn; }
    int m = min(64, e - base);
    for (int j = 0; j < m; ++j){
      int s = __shfl(sv, j);
      float w = __shfl(wv, j);
      acc += prev[(size_t)s*64 + lane] * w;
    }
  }
  cur[(size_t)n*64 + lane] = acc;
}

// ---------------- h0 = relu(x @ W_in^T + b_in) ----------------
__global__ void __launch_bounds__(256) k_h0(const float* __restrict__ x,
    const float* __restrict__ Win, const float* __restrict__ bin,
    float* __restrict__ tok0){
  __shared__ unsigned short Xs[64*264];
  __shared__ unsigned short Ws[64*264];
  __shared__ float bs[64];
  const int tid = threadIdx.x;
  for (int idx = tid; idx < 4096; idx += 256){       // Win: 64x256
    int r = idx >> 6, c0 = (idx & 63) * 4;
    float4 v = *(const float4*)(Win + r*256 + c0);
    unsigned short* d = &Ws[r*264 + c0];
    d[0]=f2us(v.x); d[1]=f2us(v.y); d[2]=f2us(v.z); d[3]=f2us(v.w);
  }
  const int n0 = blockIdx.x * 64;
  for (int idx = tid; idx < 4096; idx += 256){       // X tile: 64x256
    int r = idx >> 6, c0 = (idx & 63) * 4;
    int n = n0 + r; if (n >= NN) n = NN-1;
    float4 v = *(const float4*)(x + (size_t)n*256 + c0);
    unsigned short* d = &Xs[r*264 + c0];
    d[0]=f2us(v.x); d[1]=f2us(v.y); d[2]=f2us(v.z); d[3]=f2us(v.w);
  }
  if (tid < 64) bs[tid] = bin[tid];
  __syncthreads();
  const int w = tid >> 6, lane = tid & 63, quad = lane >> 4, c = lane & 15;
  f32x4 acc[4] = {{0,0,0,0},{0,0,0,0},{0,0,0,0},{0,0,0,0}};
  #pragma unroll
  for (int ks = 0; ks < 8; ++ks){
    int k0 = ks*32 + quad*8;
    bf16x8 a = *(const bf16x8*)&Xs[(w*16 + c)*264 + k0];
    #pragma unroll
    for (int nt = 0; nt < 4; ++nt){
      bf16x8 b = *(const bf16x8*)&Ws[(nt*16 + c)*264 + k0];
      acc[nt] = __builtin_amdgcn_mfma_f32_16x16x32_bf16(a, b, acc[nt], 0,0,0);
    }
  }
  #pragma unroll
  for (int nt = 0; nt < 4; ++nt){
    int col = nt*16 + c;
    float bb = bs[col];
    #pragma unroll
    for (int rg = 0; rg < 4; ++rg){
      int n = n0 + w*16 + quad*4 + rg;
      if (n < NN) tok0[(size_t)n*64 + col] = fmaxf(acc[nt][rg] + bb, 0.f);
    }
  }
}

// ------- token = relu(cur @ sgW^T + sgb) -------
__global__ void __launch_bounds__(256) k_token(const float* __restrict__ cur,
    const float* __restrict__ sgW, const float* __restrict__ sgb,
    float* __restrict__ tok){
  __shared__ unsigned short Xs[64*72];
  __shared__ unsigned short Ws[64*72];
  __shared__ float bs[64];
  const int tid = threadIdx.x;
  for (int idx = tid; idx < 1024; idx += 256){       // sgW: 64x64
    int r = idx >> 4, c0 = (idx & 15)*4;
    float4 v = *(const float4*)(sgW + r*64 + c0);
    unsigned short* d = &Ws[r*72 + c0];
    d[0]=f2us(v.x); d[1]=f2us(v.y); d[2]=f2us(v.z); d[3]=f2us(v.w);
  }
  if (tid < 64) bs[tid] = sgb[tid];
  const int n0 = blockIdx.x*64;
  {
    int r = tid >> 2, c0 = (tid & 3)*16;
    int n = n0 + r; if (n >= NN) n = NN-1;
    #pragma unroll
    for (int i = 0; i < 4; ++i){
      float4 v = *(const float4*)(cur + (size_t)n*64 + c0 + i*4);
      unsigned short* d = &Xs[r*72 + c0 + i*4];
      d[0]=f2us(v.x); d[1]=f2us(v.y); d[2]=f2us(v.z); d[3]=f2us(v.w);
    }
  }
  __syncthreads();
  const int w = tid >> 6, lane = tid & 63, quad = lane >> 4, c = lane & 15;
  f32x4 acc[4] = {{0,0,0,0},{0,0,0,0},{0,0,0,0},{0,0,0,0}};
  #pragma unroll
  for (int ks = 0; ks < 2; ++ks){
    int k0 = ks*32 + quad*8;
    bf16x8 a = *(const bf16x8*)&Xs[(w*16 + c)*72 + k0];
    #pragma unroll
    for (int nt = 0; nt < 4; ++nt){
      bf16x8 b = *(const bf16x8*)&Ws[(nt*16 + c)*72 + k0];
      acc[nt] = __builtin_amdgcn_mfma_f32_16x16x32_bf16(a, b, acc[nt], 0,0,0);
    }
  }
  #pragma unroll
  for (int nt = 0; nt < 4; ++nt){
    int col = nt*16 + c;
    float bb = bs[col];
    #pragma unroll
    for (int rg = 0; rg < 4; ++rg){
      int n = n0 + w*16 + quad*4 + rg;
      if (n < NN) tok[(size_t)n*64 + col] = fmaxf(acc[nt][rg] + bb, 0.f);
    }
  }
}

// ---------------- attention + LN1 (MFMA, in-place on tokens) ----------------
__global__ void __launch_bounds__(256) k_attn(float* __restrict__ tokens,
    const float* __restrict__ Wqkv, const float* __restrict__ bqkv,
    const float* __restrict__ Wo,   const float* __restrict__ bo,
    const float* __restrict__ ln1w, const float* __restrict__ ln1b){
  __shared__ unsigned short Wq[192*72];
  __shared__ unsigned short Wos[64*72];
  __shared__ unsigned short Xs[64*72];
  __shared__ unsigned short As2[64*72];
  __shared__ float bq[192], bos[64], l1w[64], l1b[64];
  const int tid = threadIdx.x;
  for (int idx = tid; idx < 3072; idx += 256){       // Wqkv: 192x64
    int r = idx >> 4, c0 = (idx & 15)*4;
    float4 v = *(const float4*)(Wqkv + r*64 + c0);
    unsigned short* d = &Wq[r*72 + c0];
    d[0]=f2us(v.x); d[1]=f2us(v.y); d[2]=f2us(v.z); d[3]=f2us(v.w);
  }
  for (int idx = tid; idx < 1024; idx += 256){       // Wo: 64x64
    int r = idx >> 4, c0 = (idx & 15)*4;
    float4 v = *(const float4*)(Wo + r*64 + c0);
    unsigned short* d = &Wos[r*72 + c0];
    d[0]=f2us(v.x); d[1]=f2us(v.y); d[2]=f2us(v.z); d[3]=f2us(v.w);
  }
  if (tid < 192) bq[tid] = bqkv[tid];
  if (tid < 64){ bos[tid]=bo[tid]; l1w[tid]=ln1w[tid]; l1b[tid]=ln1b[tid]; }
  const int g = blockIdx.x;
  {
    int r = tid >> 2, c0 = (tid & 3)*16;
    int t = r & 3, n = g*16 + (r >> 2);      // row = node_local*4 + t
    const float* src = tokens + (size_t)t*NN*64 + (size_t)n*64 + c0;
    #pragma unroll
    for (int i = 0; i < 4; ++i){
      float4 v = *(const float4*)(src + i*4);
      unsigned short* d = &Xs[r*72 + c0 + i*4];
      d[0]=f2us(v.x); d[1]=f2us(v.y); d[2]=f2us(v.z); d[3]=f2us(v.w);
    }
  }
  __syncthreads();
  const int w = tid >> 6, lane = tid & 63, quad = lane >> 4, c = lane & 15;
  const int rw = w*16;
  bf16x8 a0 = *(const bf16x8*)&Xs[(rw+c)*72 + quad*8];
  bf16x8 a1 = *(const bf16x8*)&Xs[(rw+c)*72 + 32 + quad*8];
  f32x4 qk[12];   // 0-3: q tiles, 4-7: k tiles, 8-11: v tiles
  #pragma unroll
  for (int nt = 0; nt < 12; ++nt){
    f32x4 acc = {0,0,0,0};
    bf16x8 b0 = *(const bf16x8*)&Wq[(nt*16+c)*72 + quad*8];
    bf16x8 b1 = *(const bf16x8*)&Wq[(nt*16+c)*72 + 32 + quad*8];
    acc = __builtin_amdgcn_mfma_f32_16x16x32_bf16(a0, b0, acc, 0,0,0);
    acc = __builtin_amdgcn_mfma_f32_16x16x32_bf16(a1, b1, acc, 0,0,0);
    float bb = bq[nt*16 + c];
    acc[0]+=bb; acc[1]+=bb; acc[2]+=bb; acc[3]+=bb;
    qk[nt] = acc;
  }
  // scores: node = quad (rows quad*4+reg), dims spread over lanes&tiles
  float sc[4][4];
  #pragma unroll
  for (int s = 0; s < 4; ++s){
    #pragma unroll
    for (int t = 0; t < 4; ++t){
      float p = qk[0][s]*qk[4][t] + qk[1][s]*qk[5][t]
              + qk[2][s]*qk[6][t] + qk[3][s]*qk[7][t];
      p += __shfl_xor(p, 1); p += __shfl_xor(p, 2);
      p += __shfl_xor(p, 4); p += __shfl_xor(p, 8);
      sc[s][t] = p * 0.125f;
    }
  }
  float pm[4][4];
  #pragma unroll
  for (int s = 0; s < 4; ++s){
    float m = fmaxf(fmaxf(sc[s][0],sc[s][1]), fmaxf(sc[s][2],sc[s][3]));
    float e0=__expf(sc[s][0]-m), e1=__expf(sc[s][1]-m);
    float e2=__expf(sc[s][2]-m), e3=__expf(sc[s][3]-m);
    float inv = 1.f/(e0+e1+e2+e3);
    pm[s][0]=e0*inv; pm[s][1]=e1*inv; pm[s][2]=e2*inv; pm[s][3]=e3*inv;
  }
  // a = P @ V (local per lane), write to LDS in A-layout
  #pragma unroll
  for (int tile = 0; tile < 4; ++tile){
    #pragma unroll
    for (int s = 0; s < 4; ++s){
      float av = pm[s][0]*qk[8+tile][0] + pm[s][1]*qk[8+tile][1]
               + pm[s][2]*qk[8+tile][2] + pm[s][3]*qk[8+tile][3];
      As2[(rw + quad*4 + s)*72 + tile*16 + c] = f2us(av);
    }
  }
  __syncthreads();
  // out projection
  bf16x8 p0 = *(const bf16x8*)&As2[(rw+c)*72 + quad*8];
  bf16x8 p1 = *(const bf16x8*)&As2[(rw+c)*72 + 32 + quad*8];
  f32x4 ov[4];
  #pragma unroll
  for (int nt = 0; nt < 4; ++nt){
    f32x4 acc = {0,0,0,0};
    bf16x8 b0 = *(const bf16x8*)&Wos[(nt*16+c)*72 + quad*8];
    bf16x8 b1 = *(const bf16x8*)&Wos[(nt*16+c)*72 + 32 + quad*8];
    acc = __builtin_amdgcn_mfma_f32_16x16x32_bf16(p0, b0, acc, 0,0,0);
    acc = __builtin_amdgcn_mfma_f32_16x16x32_bf16(p1, b1, acc, 0,0,0);
    ov[nt] = acc;
  }
  // residual + LN1, store back to tokens
  float r4[4][4];  // [tile][reg]
  #pragma unroll
  for (int nt = 0; nt < 4; ++nt){
    int col = nt*16 + c;
    float bb = bos[col];
    #pragma unroll
    for (int rg = 0; rg < 4; ++rg){
      float seqv = us2f(Xs[(rw + quad*4 + rg)*72 + col]);
      r4[nt][rg] = ov[nt][rg] + bb + seqv;
    }
  }
  #pragma unroll
  for (int rg = 0; rg < 4; ++rg){
    float sm = r4[0][rg]+r4[1][rg]+r4[2][rg]+r4[3][rg];
    sm += __shfl_xor(sm,1); sm += __shfl_xor(sm,2);
    sm += __shfl_xor(sm,4); sm += __shfl_xor(sm,8);
    float mean = sm * (1.f/64.f);
    float d0=r4[0][rg]-mean, d1=r4[1][rg]-mean, d2=r4[2][rg]-mean, d3=r4[3][rg]-mean;
    float vs = d0*d0+d1*d1+d2*d2+d3*d3;
    vs += __shfl_xor(vs,1); vs += __shfl_xor(vs,2);
    vs += __shfl_xor(vs,4); vs += __shfl_xor(vs,8);
    float rinv = rsqrtf(vs*(1.f/64.f) + 1e-5f);
    int row = rw + quad*4 + rg;
    int t = row & 3, n = g*16 + (row >> 2);
    float* dst = tokens + (size_t)t*NN*64 + (size_t)n*64;
    #pragma unroll
    for (int nt = 0; nt < 4; ++nt){
      int col = nt*16 + c;
      dst[col] = (r4[nt][rg] - mean) * rinv * l1w[col] + l1b[col];
    }
  }
}

// ---------------- FFN + LN2 + mean + classifier (MFMA) ----------------
__global__ void __launch_bounds__(256) k_ffn(const float* __restrict__ tokens,
    const float* __restrict__ W1, const float* __restrict__ b1,
    const float* __restrict__ W2, const float* __restrict__ b2,
    const float* __restrict__ ln2w, const float* __restrict__ ln2b,
    const float* __restrict__ Wc, const float* __restrict__ bc,
    float* __restrict__ out){
  __shared__ unsigned short W1s[128*72];
  __shared__ unsigned short W2s[64*136];
  __shared__ unsigned short Wcs[40*72];
  __shared__ unsigned short Xs[64*72];
  __shared__ unsigned short F1[64*136];
  __shared__ float hs[16*68];
  __shared__ float b1s[128], b2s[64], l2w[64], l2b[64], bcs[40];
  const int tid = threadIdx.x;
  for (int idx = tid; idx < 2048; idx += 256){       // W1: 128x64
    int r = idx >> 4, c0 = (idx & 15)*4;
    float4 v = *(const float4*)(W1 + r*64 + c0);
    unsigned short* d = &W1s[r*72 + c0];
    d[0]=f2us(v.x); d[1]=f2us(v.y); d[2]=f2us(v.z); d[3]=f2us(v.w);
  }
  for (int idx = tid; idx < 2048; idx += 256){       // W2: 64x128
    int r = idx >> 5, c0 = (idx & 31)*4;
    float4 v = *(const float4*)(W2 + r*128 + c0);
    unsigned short* d = &W2s[r*136 + c0];
    d[0]=f2us(v.x); d[1]=f2us(v.y); d[2]=f2us(v.z); d[3]=f2us(v.w);
  }
  for (int idx = tid; idx < 640; idx += 256){        // Wc: 40x64
    int r = idx >> 4, c0 = (idx & 15)*4;
    float4 v = *(const float4*)(Wc + r*64 + c0);
    unsigned short* d = &Wcs[r*72 + c0];
    d[0]=f2us(v.x); d[1]=f2us(v.y); d[2]=f2us(v.z); d[3]=f2us(v.w);
  }
  if (tid < 128) b1s[tid] = b1[tid];
  if (tid < 64){ b2s[tid]=b2[tid]; l2w[tid]=ln2w[tid]; l2b[tid]=ln2b[tid]; }
  if (tid < 40)  bcs[tid] = bc[tid];
  const int g = blockIdx.x;
  {
    int r = tid >> 2, c0 = (tid & 3)*16;
    int t = r & 3, n = g*16 + (r >> 2);
    const float* src = tokens + (size_t)t*NN*64 + (size_t)n*64 + c0;
    #pragma unroll
    for (int i = 0; i < 4; ++i){
      float4 v = *(const float4*)(src + i*4);
      unsigned short* d = &Xs[r*72 + c0 + i*4];
      d[0]=f2us(v.x); d[1]=f2us(v.y); d[2]=f2us(v.z); d[3]=f2us(v.w);
    }
  }
  __syncthreads();
  const int w = tid >> 6, lane = tid & 63, quad = lane >> 4, c = lane & 15;
  const int rw = w*16;
  bf16x8 a0 = *(const bf16x8*)&Xs[(rw+c)*72 + quad*8];
  bf16x8 a1 = *(const bf16x8*)&Xs[(rw+c)*72 + 32 + quad*8];
  // ff1 + exact gelu -> F1 (A-layout, bf16)
  #pragma unroll
  for (int nt = 0; nt < 8; ++nt){
    f32x4 acc = {0,0,0,0};
    bf16x8 b0 = *(const bf16x8*)&W1s[(nt*16+c)*72 + quad*8];
    bf16x8 b1v = *(const bf16x8*)&W1s[(nt*16+c)*72 + 32 + quad*8];
    acc = __builtin_amdgcn_mfma_f32_16x16x32_bf16(a0, b0, acc, 0,0,0);
    acc = __builtin_amdgcn_mfma_f32_16x16x32_bf16(a1, b1v, acc, 0,0,0);
    float bb = b1s[nt*16 + c];
    #pragma unroll
    for (int rg = 0; rg < 4; ++rg){
      float v = acc[rg] + bb;
      float ge = 0.5f * v * (1.f + erff(v * 0.70710678118654752f));
      F1[(rw + quad*4 + rg)*136 + nt*16 + c] = f2us(ge);
    }
  }
  __syncthreads();
  // ff2
  bf16x8 fa[4];
  #pragma unroll
  for (int ks = 0; ks < 4; ++ks)
    fa[ks] = *(const bf16x8*)&F1[(rw+c)*136 + ks*32 + quad*8];
  f32x4 ov[4];
  #pragma unroll
  for (int nt = 0; nt < 4; ++nt){
    f32x4 acc = {0,0,0,0};
    #pragma unroll
    for (int ks = 0; ks < 4; ++ks){
      bf16x8 b = *(const bf16x8*)&W2s[(nt*16+c)*136 + ks*32 + quad*8];
      acc = __builtin_amdgcn_mfma_f32_16x16x32_bf16(fa[ks], b, acc, 0,0,0);
    }
    ov[nt] = acc;
  }
  // residual + LN2 + token-mean
  float r4[4][4];
  #pragma unroll
  for (int nt = 0; nt < 4; ++nt){
    int col = nt*16 + c;
    float bb = b2s[col];
    #pragma unroll
    for (int rg = 0; rg < 4; ++rg){
      float seqv = us2f(Xs[(rw + quad*4 + rg)*72 + col]);
      r4[nt][rg] = ov[nt][rg] + bb + seqv;
    }
  }
  float hval[4] = {0.f, 0.f, 0.f, 0.f};
  #pragma unroll
  for (int rg = 0; rg < 4; ++rg){
    float sm = r4[0][rg]+r4[1][rg]+r4[2][rg]+r4[3][rg];
    sm += __shfl_xor(sm,1); sm += __shfl_xor(sm,2);
    sm += __shfl_xor(sm,4); sm += __shfl_xor(sm,8);
    float mean = sm * (1.f/64.f);
    float d0=r4[0][rg]-mean, d1=r4[1][rg]-mean, d2=r4[2][rg]-mean, d3=r4[3][rg]-mean;
    float vs = d0*d0+d1*d1+d2*d2+d3*d3;
    vs += __shfl_xor(vs,1); vs += __shfl_xor(vs,2);
    vs += __shfl_xor(vs,4); vs += __shfl_xor(vs,8);
    float rinv = rsqrtf(vs*(1.f/64.f) + 1e-5f);
    #pragma unroll
    for (int nt = 0; nt < 4; ++nt){
      int col = nt*16 + c;
      hval[nt] += (r4[nt][rg] - mean) * rinv * l2w[col] + l2b[col];
    }
  }
  #pragma unroll
  for (int nt = 0; nt < 4; ++nt)
    hs[(w*4 + quad)*68 + nt*16 + c] = hval[nt] * 0.25f;
  __syncthreads();
  // classifier: 16 nodes x 40 outs
  for (int p = tid; p < 16*OUTC; p += 256){
    int node = p / OUTC, o = p - node*OUTC;
    float acc = bcs[o];
    const unsigned* wrow = (const unsigned*)&Wcs[o*72];
    const float2*  hrow = (const float2*)&hs[node*68];
    #pragma unroll 8
    for (int j2 = 0; j2 < 32; ++j2){
      unsigned u = wrow[j2];
      float2 hv = hrow[j2];
      acc += hv.x*lo_f(u) + hv.y*hi_f(u);
    }
    out[(size_t)(g*16 + node)*OUTC + o] = acc;
  }
}

extern "C" void kernel_launch(void* const* d_in, const int* in_sizes, int n_in,
                              void* d_out, int out_size, void* d_ws, size_t ws_size,
                              hipStream_t stream) {
  const float* x    = (const float*)d_in[0];
  const int*   ei   = (const int*  )d_in[1];
  const float* Win  = (const float*)d_in[2];
  const float* bin  = (const float*)d_in[3];
  const float* sgW  = (const float*)d_in[4];
  const float* sgb  = (const float*)d_in[5];
  const float* Wqkv = (const float*)d_in[6];
  const float* bqkv = (const float*)d_in[7];
  const float* Wo   = (const float*)d_in[8];
  const float* bo   = (const float*)d_in[9];
  const float* W1   = (const float*)d_in[10];
  const float* b1   = (const float*)d_in[11];
  const float* W2   = (const float*)d_in[12];
  const float* b2   = (const float*)d_in[13];
  const float* ln1w = (const float*)d_in[14];
  const float* ln1b = (const float*)d_in[15];
  const float* ln2w = (const float*)d_in[16];
  const float* ln2b = (const float*)d_in[17];
  const float* Wc   = (const float*)d_in[18];
  const float* bc   = (const float*)d_in[19];

  char* ws = (char*)d_ws;
  float* dinv   = (float*)(ws);                    // 400,000 B
  int*   fill   = (int*  )(ws + 400128);           // 400,000 B (prefix -> bump)
  float* tokens = (float*)(ws + 800256);           // 4*N*64*4 = 102,400,000 B
  float* pbuf0  = (float*)(ws + 103200256);        // 25,600,000 B
  float* pbuf1  = (float*)(ws + 128800256);        // 25,600,000 B
  // scratch aliased into the (not-yet-written) hop-3 token slot (25.6 MB):
  //   csr_src: 6.4 MB | cnt: 400 KB | bsum: ~1.6 KB   (total ~6.8 MB)
  int*   csr_src = (int*)(tokens + (size_t)3*NN*64);
  int*   cnt     = csr_src + EE;
  int*   bsum    = cnt + NN;

  // --- CSR build (once; reused by all 3 hops) ---
  k_zero <<<(NN+255)/256, 256, 0, stream>>>(cnt);
  k_cnt  <<<(EE+255)/256, 256, 0, stream>>>(ei, cnt);
  k_bsum <<<NB, 256, 0, stream>>>(cnt, bsum);
  k_scanb<<<1, 512, 0, stream>>>(bsum);
  k_scan2<<<NB, 256, 0, stream>>>(cnt, bsum, fill, dinv);
  k_fill <<<(EE+255)/256, 256, 0, stream>>>(ei, fill, csr_src);

  const int GB = (NN + 63) / 64;                   // 1563
  const int GG = (NN*64 + 255) / 256;              // 25000 (wave per node)
  k_h0<<<GB, 256, 0, stream>>>(x, Win, bin, tokens);

  // hop 1
  k_gather<<<GG, 256, 0, stream>>>(fill, csr_src, dinv, tokens, pbuf0);
  k_token <<<GB, 256, 0, stream>>>(pbuf0, sgW, sgb, tokens + (size_t)1*NN*64);
  // hop 2
  k_gather<<<GG, 256, 0, stream>>>(fill, csr_src, dinv, pbuf0, pbuf1);
  k_token <<<GB, 256, 0, stream>>>(pbuf1, sgW + 4096, sgb + 64, tokens + (size_t)2*NN*64);
  // hop 3
  k_gather<<<GG, 256, 0, stream>>>(fill, csr_src, dinv, pbuf1, pbuf0);
  k_token <<<GB, 256, 0, stream>>>(pbuf0, sgW + 8192, sgb + 128, tokens + (size_t)3*NN*64);

  k_attn<<<NN/16, 256, 0, stream>>>(tokens, Wqkv, bqkv, Wo, bo, ln1w, ln1b);
  k_ffn<<<NN/16, 256, 0, stream>>>(tokens, W1, b1, W2, b2, ln2w, ln2b, Wc, bc,
                                   (float*)d_out);
}

// Round 6
// 935.413 us; speedup vs baseline: 3.3591x; 1.0627x over previous
//
#include <hip/hip_runtime.h>
#include <hip/hip_bf16.h>
#include <math.h>

#define NN 100000
#define EE 1600000
#define OUTC 40
#define NB 391            // (NN+255)/256
#define NG 6250           // NN/16 groups for attn/ffn

// prepacked-weight offsets (in shorts), padded to LDS strides
#define WP_WIN 0          // 64 x 264   (Win 64x256)
#define WP_SG  16896      // 3 x 64 x 72 (sgW 3x64x64)
#define WP_QKV 30720      // 192 x 72
#define WP_WO  44544      // 64 x 72
#define WP_W1  49152      // 128 x 72
#define WP_W2  58368      // 64 x 136  (W2 64x128)
#define WP_WC  67072      // 40 x 72
#define WP_TOT 69952

typedef __hip_bfloat16 bf16;
typedef __attribute__((ext_vector_type(8))) short bf16x8;
typedef __attribute__((ext_vector_type(4))) float f32x4;

__device__ __forceinline__ unsigned short f2us(float f){
  bf16 b = __float2bfloat16(f);
  unsigned short u; __builtin_memcpy(&u, &b, 2); return u;
}
__device__ __forceinline__ float us2f(unsigned short u){
  union{unsigned x; float f;} c; c.x = ((unsigned)u)<<16; return c.f;
}
__device__ __forceinline__ float lo_f(unsigned u){ union{unsigned x;float f;}c; c.x = u<<16; return c.f; }
__device__ __forceinline__ float hi_f(unsigned u){ union{unsigned x;float f;}c; c.x = u & 0xffff0000u; return c.f; }

// ---------------- weight prepack (fp32 -> bf16, LDS-image layouts) ----------------
__global__ void k_wprep(const float* __restrict__ Win, const float* __restrict__ sgW,
                        const float* __restrict__ Wqkv, const float* __restrict__ Wo,
                        const float* __restrict__ W1, const float* __restrict__ W2,
                        const float* __restrict__ Wc, unsigned short* __restrict__ wp){
  for (int idx = blockIdx.x*blockDim.x + threadIdx.x; idx < WP_TOT;
       idx += gridDim.x*blockDim.x){
    float v; int o;
    if (idx < WP_SG){ o = idx; int r=o/264, c=o-r*264; v = (c<256)? Win[r*256+c] : 0.f; }
    else if (idx < WP_QKV){ o = idx-WP_SG; int h=o/4608, rem=o-h*4608, r=rem/72, c=rem-r*72;
      v=(c<64)? sgW[h*4096+r*64+c] : 0.f; }
    else if (idx < WP_WO){ o = idx-WP_QKV; int r=o/72, c=o-r*72; v=(c<64)? Wqkv[r*64+c]:0.f; }
    else if (idx < WP_W1){ o = idx-WP_WO; int r=o/72, c=o-r*72; v=(c<64)? Wo[r*64+c]:0.f; }
    else if (idx < WP_W2){ o = idx-WP_W1; int r=o/72, c=o-r*72; v=(c<64)? W1[r*64+c]:0.f; }
    else if (idx < WP_WC){ o = idx-WP_W2; int r=o/136, c=o-r*136; v=(c<128)? W2[r*128+c]:0.f; }
    else { o = idx-WP_WC; int r=o/72, c=o-r*72; v=(c<64)? Wc[r*64+c]:0.f; }
    wp[idx] = f2us(v);
  }
}

// ---------------- CSR build ----------------
__global__ void k_zero(int* cnt){
  int i = blockIdx.x*blockDim.x + threadIdx.x;
  if (i < NN) cnt[i] = 0;
}
__global__ void k_cnt(const int* __restrict__ ei, int* cnt){
  int e = blockIdx.x*blockDim.x + threadIdx.x;
  if (e < EE) atomicAdd(&cnt[ei[EE + e]], 1);
}
__global__ void __launch_bounds__(256) k_bsum(const int* __restrict__ cnt, int* __restrict__ bsum){
  __shared__ int wsum[4];
  int i = blockIdx.x*256 + threadIdx.x;
  int v = (i < NN) ? cnt[i] : 0;
  #pragma unroll
  for (int m = 1; m < 64; m <<= 1) v += __shfl_xor(v, m);
  if ((threadIdx.x & 63) == 0) wsum[threadIdx.x >> 6] = v;
  __syncthreads();
  if (threadIdx.x == 0) bsum[blockIdx.x] = wsum[0] + wsum[1] + wsum[2] + wsum[3];
}
__global__ void __launch_bounds__(512) k_scanb(int* bsum){
  __shared__ int sh[512];
  const int t = threadIdx.x;
  int v = (t < NB) ? bsum[t] : 0;
  sh[t] = v;
  __syncthreads();
  int acc = v;
  for (int st = 1; st < 512; st <<= 1){
    int add = (t >= st) ? sh[t - st] : 0;
    __syncthreads();
    acc += add; sh[t] = acc;
    __syncthreads();
  }
  if (t < NB) bsum[t] = acc - v;   // exclusive
}
__global__ void __launch_bounds__(256) k_scan2(const int* __restrict__ cnt,
    const int* __restrict__ bsum, int* __restrict__ fill, float* __restrict__ dinv){
  __shared__ int sh[256];
  const int t = threadIdx.x;
  int i = blockIdx.x*256 + t;
  int c = (i < NN) ? cnt[i] : 0;
  sh[t] = c;
  __syncthreads();
  int acc = c;
  for (int st = 1; st < 256; st <<= 1){
    int add = (t >= st) ? sh[t - st] : 0;
    __syncthreads();
    acc += add; sh[t] = acc;
    __syncthreads();
  }
  if (i < NN){
    fill[i] = bsum[blockIdx.x] + acc - c;
    dinv[i] = rsqrtf((float)c + 1.0f);
  }
}
__global__ void k_fill(const int* __restrict__ ei, int* fill, int* csr_src){
  int e = blockIdx.x*blockDim.x + threadIdx.x;
  if (e < EE){
    int d = ei[EE + e];
    int p = atomicAdd(&fill[d], 1);
    csr_src[p] = ei[e];
  }
}

// ---------------- gather propagation: cur = S @ prev (no atomics) ----------------
__global__ void __launch_bounds__(256) k_gather(const int* __restrict__ fill,
    const int* __restrict__ csr_src, const float* __restrict__ dinv,
    const float* __restrict__ prev, float* __restrict__ cur){
  int wid = (blockIdx.x*256 + threadIdx.x) >> 6;
  int lane = threadIdx.x & 63;
  if (wid >= NN) return;
  const int n = wid;
  int b = (n == 0) ? 0 : fill[n-1];
  int e = fill[n];
  float dn = dinv[n];
  float acc = prev[(size_t)n*64 + lane] * dn * dn;
  for (int base = b; base < e; base += 64){
    int idx = base + lane;
    int sv = 0; float wv = 0.f;
    if (idx < e){ sv = csr_src[idx]; wv = dinv[sv] * dn; }
    int m = min(64, e - base);
    for (int j = 0; j < m; ++j){
      int s = __shfl(sv, j);
      float w = __shfl(wv, j);
      acc += prev[(size_t)s*64 + lane] * w;
    }
  }
  cur[(size_t)n*64 + lane] = acc;
}

// ------- h0 = relu(x @ W_in^T + b_in): tok0 (bf16) + h0f (fp32, for hop-1) -------
__global__ void __launch_bounds__(256) k_h0(const float* __restrict__ x,
    const unsigned short* __restrict__ wp, const float* __restrict__ bin,
    unsigned short* __restrict__ tokB, float* __restrict__ h0f){
  __shared__ __align__(16) unsigned short Xs[64*264];
  __shared__ __align__(16) unsigned short Ws[64*264];
  __shared__ float bs[64];
  const int tid = threadIdx.x;
  {
    const uint4* src = (const uint4*)(wp + WP_WIN);
    for (int idx = tid; idx < 2112; idx += 256) ((uint4*)Ws)[idx] = src[idx];
  }
  const int n0 = blockIdx.x * 64;
  for (int idx = tid; idx < 4096; idx += 256){       // X tile: 64x256, fp32->bf16
    int r = idx >> 6, c0 = (idx & 63) * 4;
    int n = n0 + r; if (n >= NN) n = NN-1;
    float4 v = *(const float4*)(x + (size_t)n*256 + c0);
    unsigned short* d = &Xs[r*264 + c0];
    d[0]=f2us(v.x); d[1]=f2us(v.y); d[2]=f2us(v.z); d[3]=f2us(v.w);
  }
  if (tid < 64) bs[tid] = bin[tid];
  __syncthreads();
  const int w = tid >> 6, lane = tid & 63, quad = lane >> 4, c = lane & 15;
  f32x4 acc[4] = {{0,0,0,0},{0,0,0,0},{0,0,0,0},{0,0,0,0}};
  #pragma unroll
  for (int ks = 0; ks < 8; ++ks){
    int k0 = ks*32 + quad*8;
    bf16x8 a = *(const bf16x8*)&Xs[(w*16 + c)*264 + k0];
    #pragma unroll
    for (int nt = 0; nt < 4; ++nt){
      bf16x8 b = *(const bf16x8*)&Ws[(nt*16 + c)*264 + k0];
      acc[nt] = __builtin_amdgcn_mfma_f32_16x16x32_bf16(a, b, acc[nt], 0,0,0);
    }
  }
  __syncthreads();
  #pragma unroll
  for (int nt = 0; nt < 4; ++nt){
    int col = nt*16 + c;
    float bb = bs[col];
    #pragma unroll
    for (int rg = 0; rg < 4; ++rg){
      int rloc = w*16 + quad*4 + rg;
      int n = n0 + rloc;
      float v = fmaxf(acc[nt][rg] + bb, 0.f);
      Xs[rloc*72 + col] = f2us(v);
      if (n < NN) h0f[(size_t)n*64 + col] = v;
    }
  }
  __syncthreads();
  for (int idx = tid; idx < 512; idx += 256){
    int r = idx >> 3, ch = idx & 7;
    int n = n0 + r;
    if (n < NN)
      *(uint4*)(tokB + (size_t)n*64 + ch*8) = *(const uint4*)&Xs[r*72 + ch*8];
  }
}

// ------- token = relu(cur @ sgW^T + sgb) -> bf16 tokens -------
__global__ void __launch_bounds__(256) k_token(const float* __restrict__ cur,
    const unsigned short* __restrict__ wsg, const float* __restrict__ sgb,
    unsigned short* __restrict__ tok){
  __shared__ __align__(16) unsigned short Xs[64*72];
  __shared__ __align__(16) unsigned short Ws[64*72];
  __shared__ float bs[64];
  const int tid = threadIdx.x;
  {
    const uint4* src = (const uint4*)wsg;
    for (int idx = tid; idx < 576; idx += 256) ((uint4*)Ws)[idx] = src[idx];
  }
  if (tid < 64) bs[tid] = sgb[tid];
  const int n0 = blockIdx.x*64;
  {
    int r = tid >> 2, c0 = (tid & 3)*16;
    int n = n0 + r; if (n >= NN) n = NN-1;
    #pragma unroll
    for (int i = 0; i < 4; ++i){
      float4 v = *(const float4*)(cur + (size_t)n*64 + c0 + i*4);
      unsigned short* d = &Xs[r*72 + c0 + i*4];
      d[0]=f2us(v.x); d[1]=f2us(v.y); d[2]=f2us(v.z); d[3]=f2us(v.w);
    }
  }
  __syncthreads();
  const int w = tid >> 6, lane = tid & 63, quad = lane >> 4, c = lane & 15;
  f32x4 acc[4] = {{0,0,0,0},{0,0,0,0},{0,0,0,0},{0,0,0,0}};
  #pragma unroll
  for (int ks = 0; ks < 2; ++ks){
    int k0 = ks*32 + quad*8;
    bf16x8 a = *(const bf16x8*)&Xs[(w*16 + c)*72 + k0];
    #pragma unroll
    for (int nt = 0; nt < 4; ++nt){
      bf16x8 b = *(const bf16x8*)&Ws[(nt*16 + c)*72 + k0];
      acc[nt] = __builtin_amdgcn_mfma_f32_16x16x32_bf16(a, b, acc[nt], 0,0,0);
    }
  }
  __syncthreads();
  #pragma unroll
  for (int nt = 0; nt < 4; ++nt){
    int col = nt*16 + c;
    float bb = bs[col];
    #pragma unroll
    for (int rg = 0; rg < 4; ++rg){
      int rloc = w*16 + quad*4 + rg;
      Xs[rloc*72 + col] = f2us(fmaxf(acc[nt][rg] + bb, 0.f));
    }
  }
  __syncthreads();
  for (int idx = tid; idx < 512; idx += 256){
    int r = idx >> 3, ch = idx & 7;
    int n = n0 + r;
    if (n < NN)
      *(uint4*)(tok + (size_t)n*64 + ch*8) = *(const uint4*)&Xs[r*72 + ch*8];
  }
}

// ---------------- attention + LN1 (persistent, bf16 tokens in-place) ----------------
__global__ void __launch_bounds__(256) k_attn(unsigned short* __restrict__ tokB,
    const unsigned short* __restrict__ wp, const float* __restrict__ bqkv,
    const float* __restrict__ bo, const float* __restrict__ ln1w,
    const float* __restrict__ ln1b){
  __shared__ __align__(16) unsigned short Wq[192*72];
  __shared__ __align__(16) unsigned short Wos[64*72];
  __shared__ __align__(16) unsigned short Xs[64*72];
  __shared__ __align__(16) unsigned short As2[64*72];
  __shared__ float bq[192], bos[64], l1w[64], l1b[64];
  const int tid = threadIdx.x;
  {
    const uint4* s1 = (const uint4*)(wp + WP_QKV);
    for (int idx = tid; idx < 1728; idx += 256) ((uint4*)Wq)[idx] = s1[idx];
    const uint4* s2 = (const uint4*)(wp + WP_WO);
    for (int idx = tid; idx < 576; idx += 256) ((uint4*)Wos)[idx] = s2[idx];
  }
  if (tid < 192) bq[tid] = bqkv[tid];
  if (tid < 64){ bos[tid]=bo[tid]; l1w[tid]=ln1w[tid]; l1b[tid]=ln1b[tid]; }
  const int w = tid >> 6, lane = tid & 63, quad = lane >> 4, c = lane & 15;
  const int rw = w*16;
  for (int g = blockIdx.x; g < NG; g += gridDim.x){
    __syncthreads();        // protect Xs/As2 from previous iteration readers
    for (int idx = tid; idx < 512; idx += 256){     // stage 64 rows of bf16 tokens
      int r = idx >> 3, ch = idx & 7;
      int t = r & 3, n = g*16 + (r >> 2);           // row = node_local*4 + t
      *(uint4*)&Xs[r*72 + ch*8] = *(const uint4*)(tokB + ((size_t)t*NN + n)*64 + ch*8);
    }
    __syncthreads();
    bf16x8 a0 = *(const bf16x8*)&Xs[(rw+c)*72 + quad*8];
    bf16x8 a1 = *(const bf16x8*)&Xs[(rw+c)*72 + 32 + quad*8];
    f32x4 qk[12];   // 0-3: q tiles, 4-7: k tiles, 8-11: v tiles
    #pragma unroll
    for (int nt = 0; nt < 12; ++nt){
      f32x4 acc = {0,0,0,0};
      bf16x8 b0 = *(const bf16x8*)&Wq[(nt*16+c)*72 + quad*8];
      bf16x8 b1 = *(const bf16x8*)&Wq[(nt*16+c)*72 + 32 + quad*8];
      acc = __builtin_amdgcn_mfma_f32_16x16x32_bf16(a0, b0, acc, 0,0,0);
      acc = __builtin_amdgcn_mfma_f32_16x16x32_bf16(a1, b1, acc, 0,0,0);
      float bb = bq[nt*16 + c];
      acc[0]+=bb; acc[1]+=bb; acc[2]+=bb; acc[3]+=bb;
      qk[nt] = acc;
    }
    float sc[4][4];
    #pragma unroll
    for (int s = 0; s < 4; ++s){
      #pragma unroll
      for (int t = 0; t < 4; ++t){
        float p = qk[0][s]*qk[4][t] + qk[1][s]*qk[5][t]
                + qk[2][s]*qk[6][t] + qk[3][s]*qk[7][t];
        p += __shfl_xor(p, 1); p += __shfl_xor(p, 2);
        p += __shfl_xor(p, 4); p += __shfl_xor(p, 8);
        sc[s][t] = p * 0.125f;
      }
    }
    float pm[4][4];
    #pragma unroll
    for (int s = 0; s < 4; ++s){
      float m = fmaxf(fmaxf(sc[s][0],sc[s][1]), fmaxf(sc[s][2],sc[s][3]));
      float e0=__expf(sc[s][0]-m), e1=__expf(sc[s][1]-m);
      float e2=__expf(sc[s][2]-m), e3=__expf(sc[s][3]-m);
      float inv = 1.f/(e0+e1+e2+e3);
      pm[s][0]=e0*inv; pm[s][1]=e1*inv; pm[s][2]=e2*inv; pm[s][3]=e3*inv;
    }
    // P@V -> As2 in A-layout (wave-private rows; same-wave LDS is in-order)
    #pragma unroll
    for (int tile = 0; tile < 4; ++tile){
      #pragma unroll
      for (int s = 0; s < 4; ++s){
        float av = pm[s][0]*qk[8+tile][0] + pm[s][1]*qk[8+tile][1]
                 + pm[s][2]*qk[8+tile][2] + pm[s][3]*qk[8+tile][3];
        As2[(rw + quad*4 + s)*72 + tile*16 + c] = f2us(av);
      }
    }
    bf16x8 p0 = *(const bf16x8*)&As2[(rw+c)*72 + quad*8];
    bf16x8 p1 = *(const bf16x8*)&As2[(rw+c)*72 + 32 + quad*8];
    f32x4 ov[4];
    #pragma unroll
    for (int nt = 0; nt < 4; ++nt){
      f32x4 acc = {0,0,0,0};
      bf16x8 b0 = *(const bf16x8*)&Wos[(nt*16+c)*72 + quad*8];
      bf16x8 b1 = *(const bf16x8*)&Wos[(nt*16+c)*72 + 32 + quad*8];
      acc = __builtin_amdgcn_mfma_f32_16x16x32_bf16(p0, b0, acc, 0,0,0);
      acc = __builtin_amdgcn_mfma_f32_16x16x32_bf16(p1, b1, acc, 0,0,0);
      ov[nt] = acc;
    }
    float r4[4][4];
    #pragma unroll
    for (int nt = 0; nt < 4; ++nt){
      int col = nt*16 + c;
      float bb = bos[col];
      #pragma unroll
      for (int rg = 0; rg < 4; ++rg){
        float seqv = us2f(Xs[(rw + quad*4 + rg)*72 + col]);
        r4[nt][rg] = ov[nt][rg] + bb + seqv;
      }
    }
    #pragma unroll
    for (int rg = 0; rg < 4; ++rg){
      float sm = r4[0][rg]+r4[1][rg]+r4[2][rg]+r4[3][rg];
      sm += __shfl_xor(sm,1); sm += __shfl_xor(sm,2);
      sm += __shfl_xor(sm,4); sm += __shfl_xor(sm,8);
      float mean = sm * (1.f/64.f);
      float d0=r4[0][rg]-mean, d1=r4[1][rg]-mean, d2=r4[2][rg]-mean, d3=r4[3][rg]-mean;
      float vs = d0*d0+d1*d1+d2*d2+d3*d3;
      vs += __shfl_xor(vs,1); vs += __shfl_xor(vs,2);
      vs += __shfl_xor(vs,4); vs += __shfl_xor(vs,8);
      float rinv = rsqrtf(vs*(1.f/64.f) + 1e-5f);
      int row = rw + quad*4 + rg;
      #pragma unroll
      for (int nt = 0; nt < 4; ++nt){
        int col = nt*16 + c;
        As2[row*72 + col] = f2us((r4[nt][rg] - mean) * rinv * l1w[col] + l1b[col]);
      }
    }
    __syncthreads();
    for (int idx = tid; idx < 512; idx += 256){     // coalesced copy-out
      int r = idx >> 3, ch = idx & 7;
      int t = r & 3, n = g*16 + (r >> 2);
      *(uint4*)(tokB + ((size_t)t*NN + n)*64 + ch*8) = *(const uint4*)&As2[r*72 + ch*8];
    }
  }
}

// ---------------- FFN + LN2 + mean + classifier (persistent) ----------------
__global__ void __launch_bounds__(256) k_ffn(const unsigned short* __restrict__ tokB,
    const unsigned short* __restrict__ wp,
    const float* __restrict__ b1, const float* __restrict__ b2,
    const float* __restrict__ ln2w, const float* __restrict__ ln2b,
    const float* __restrict__ bc, float* __restrict__ out){
  __shared__ __align__(16) unsigned short W1s[128*72];
  __shared__ __align__(16) unsigned short W2s[64*136];
  __shared__ __align__(16) unsigned short Wcs[40*72];
  __shared__ __align__(16) unsigned short Xs[64*72];
  __shared__ __align__(16) unsigned short F1[64*136];
  __shared__ float hs[16*68];
  __shared__ float b1s[128], b2s[64], l2w[64], l2b[64], bcs[40];
  const int tid = threadIdx.x;
  {
    const uint4* s1 = (const uint4*)(wp + WP_W1);
    for (int idx = tid; idx < 1152; idx += 256) ((uint4*)W1s)[idx] = s1[idx];
    const uint4* s2 = (const uint4*)(wp + WP_W2);
    for (int idx = tid; idx < 1088; idx += 256) ((uint4*)W2s)[idx] = s2[idx];
    const uint4* s3 = (const uint4*)(wp + WP_WC);
    for (int idx = tid; idx < 360; idx += 256) ((uint4*)Wcs)[idx] = s3[idx];
  }
  if (tid < 128) b1s[tid] = b1[tid];
  if (tid < 64){ b2s[tid]=b2[tid]; l2w[tid]=ln2w[tid]; l2b[tid]=ln2b[tid]; }
  if (tid < 40)  bcs[tid] = bc[tid];
  const int w = tid >> 6, lane = tid & 63, quad = lane >> 4, c = lane & 15;
  const int rw = w*16;
  for (int g = blockIdx.x; g < NG; g += gridDim.x){
    __syncthreads();
    for (int idx = tid; idx < 512; idx += 256){
      int r = idx >> 3, ch = idx & 7;
      int t = r & 3, n = g*16 + (r >> 2);
      *(uint4*)&Xs[r*72 + ch*8] = *(const uint4*)(tokB + ((size_t)t*NN + n)*64 + ch*8);
    }
    __syncthreads();
    bf16x8 a0 = *(const bf16x8*)&Xs[(rw+c)*72 + quad*8];
    bf16x8 a1 = *(const bf16x8*)&Xs[(rw+c)*72 + 32 + quad*8];
    // ff1 + exact gelu -> F1 (A-layout bf16, wave-private rows)
    #pragma unroll
    for (int nt = 0; nt < 8; ++nt){
      f32x4 acc = {0,0,0,0};
      bf16x8 b0 = *(const bf16x8*)&W1s[(nt*16+c)*72 + quad*8];
      bf16x8 b1v = *(const bf16x8*)&W1s[(nt*16+c)*72 + 32 + quad*8];
      acc = __builtin_amdgcn_mfma_f32_16x16x32_bf16(a0, b0, acc, 0,0,0);
      acc = __builtin_amdgcn_mfma_f32_16x16x32_bf16(a1, b1v, acc, 0,0,0);
      float bb = b1s[nt*16 + c];
      #pragma unroll
      for (int rg = 0; rg < 4; ++rg){
        float v = acc[rg] + bb;
        float ge = 0.5f * v * (1.f + erff(v * 0.70710678118654752f));
        F1[(rw + quad*4 + rg)*136 + nt*16 + c] = f2us(ge);
      }
    }
    // ff2 (same-wave LDS in-order: reads see this wave's F1 writes)
    bf16x8 fa[4];
    #pragma unroll
    for (int ks = 0; ks < 4; ++ks)
      fa[ks] = *(const bf16x8*)&F1[(rw+c)*136 + ks*32 + quad*8];
    f32x4 ov[4];
    #pragma unroll
    for (int nt = 0; nt < 4; ++nt){
      f32x4 acc = {0,0,0,0};
      #pragma unroll
      for (int ks = 0; ks < 4; ++ks){
        bf16x8 b = *(const bf16x8*)&W2s[(nt*16+c)*136 + ks*32 + quad*8];
        acc = __builtin_amdgcn_mfma_f32_16x16x32_bf16(fa[ks], b, acc, 0,0,0);
      }
      ov[nt] = acc;
    }
    float r4[4][4];
    #pragma unroll
    for (int nt = 0; nt < 4; ++nt){
      int col = nt*16 + c;
      float bb = b2s[col];
      #pragma unroll
      for (int rg = 0; rg < 4; ++rg){
        float seqv = us2f(Xs[(rw + quad*4 + rg)*72 + col]);
        r4[nt][rg] = ov[nt][rg] + bb + seqv;
      }
    }
    float hval[4] = {0.f, 0.f, 0.f, 0.f};
    #pragma unroll
    for (int rg = 0; rg < 4; ++rg){
      float sm = r4[0][rg]+r4[1][rg]+r4[2][rg]+r4[3][rg];
      sm += __shfl_xor(sm,1); sm += __shfl_xor(sm,2);
      sm += __shfl_xor(sm,4); sm += __shfl_xor(sm,8);
      float mean = sm * (1.f/64.f);
      float d0=r4[0][rg]-mean, d1=r4[1][rg]-mean, d2=r4[2][rg]-mean, d3=r4[3][rg]-mean;
      float vs = d0*d0+d1*d1+d2*d2+d3*d3;
      vs += __shfl_xor(vs,1); vs += __shfl_xor(vs,2);
      vs += __shfl_xor(vs,4); vs += __shfl_xor(vs,8);
      float rinv = rsqrtf(vs*(1.f/64.f) + 1e-5f);
      #pragma unroll
      for (int nt = 0; nt < 4; ++nt){
        int col = nt*16 + c;
        hval[nt] += (r4[nt][rg] - mean) * rinv * l2w[col] + l2b[col];
      }
    }
    #pragma unroll
    for (int nt = 0; nt < 4; ++nt)
      hs[(w*4 + quad)*68 + nt*16 + c] = hval[nt] * 0.25f;
    __syncthreads();
    for (int p = tid; p < 16*OUTC; p += 256){
      int node = p / OUTC, o = p - node*OUTC;
      float acc = bcs[o];
      const unsigned* wrow = (const unsigned*)&Wcs[o*72];
      const float2*  hrow = (const float2*)&hs[node*68];
      #pragma unroll 8
      for (int j2 = 0; j2 < 32; ++j2){
        unsigned u = wrow[j2];
        float2 hv = hrow[j2];
        acc += hv.x*lo_f(u) + hv.y*hi_f(u);
      }
      out[(size_t)(g*16 + node)*OUTC + o] = acc;
    }
  }
}

extern "C" void kernel_launch(void* const* d_in, const int* in_sizes, int n_in,
                              void* d_out, int out_size, void* d_ws, size_t ws_size,
                              hipStream_t stream) {
  const float* x    = (const float*)d_in[0];
  const int*   ei   = (const int*  )d_in[1];
  const float* Win  = (const float*)d_in[2];
  const float* bin  = (const float*)d_in[3];
  const float* sgW  = (const float*)d_in[4];
  const float* sgb  = (const float*)d_in[5];
  const float* Wqkv = (const float*)d_in[6];
  const float* bqkv = (const float*)d_in[7];
  const float* Wo   = (const float*)d_in[8];
  const float* bo   = (const float*)d_in[9];
  const float* W1   = (const float*)d_in[10];
  const float* b1   = (const float*)d_in[11];
  const float* W2   = (const float*)d_in[12];
  const float* b2   = (const float*)d_in[13];
  const float* ln1w = (const float*)d_in[14];
  const float* ln1b = (const float*)d_in[15];
  const float* ln2w = (const float*)d_in[16];
  const float* ln2b = (const float*)d_in[17];
  const float* Wc   = (const float*)d_in[18];
  const float* bc   = (const float*)d_in[19];

  char* ws = (char*)d_ws;
  float*          dinv = (float*)(ws);                      // 400,000 B
  int*            fill = (int*  )(ws + 400128);             // 400,000 B
  unsigned short* wp   = (unsigned short*)(ws + 800256);    // 139,904 B prepacked weights
  unsigned short* tokB = (unsigned short*)(ws + 940288);    // 4*N*64*2 = 51,200,000 B
  float*          h0f  = (float*)(ws + 52140416);           // 25,600,000 B
  float*          pbuf0= (float*)(ws + 77740544);           // 25,600,000 B
  float*          pbuf1= (float*)(ws + 103340672);          // 25,600,000 B
  // CSR scratch aliased into the (not-yet-written) hop-3 token slot (12.8 MB):
  int* csr_src = (int*)(tokB + (size_t)3*NN*64);            // 6.4 MB
  int* cnt     = csr_src + EE;                              // 400 KB
  int* bsum    = cnt + NN;                                  // ~1.6 KB

  k_wprep<<<128, 256, 0, stream>>>(Win, sgW, Wqkv, Wo, W1, W2, Wc, wp);

  // --- CSR build (once; reused by all 3 hops) ---
  k_zero <<<(NN+255)/256, 256, 0, stream>>>(cnt);
  k_cnt  <<<(EE+255)/256, 256, 0, stream>>>(ei, cnt);
  k_bsum <<<NB, 256, 0, stream>>>(cnt, bsum);
  k_scanb<<<1, 512, 0, stream>>>(bsum);
  k_scan2<<<NB, 256, 0, stream>>>(cnt, bsum, fill, dinv);
  k_fill <<<(EE+255)/256, 256, 0, stream>>>(ei, fill, csr_src);

  const int GB = (NN + 63) / 64;                   // 1563
  const int GG = (NN*64 + 255) / 256;              // 25000 (wave per node)
  k_h0<<<GB, 256, 0, stream>>>(x, wp, bin, tokB, h0f);

  // hop 1
  k_gather<<<GG, 256, 0, stream>>>(fill, csr_src, dinv, h0f, pbuf0);
  k_token <<<GB, 256, 0, stream>>>(pbuf0, wp + WP_SG,        sgb,       tokB + (size_t)1*NN*64);
  // hop 2
  k_gather<<<GG, 256, 0, stream>>>(fill, csr_src, dinv, pbuf0, pbuf1);
  k_token <<<GB, 256, 0, stream>>>(pbuf1, wp + WP_SG + 4608, sgb + 64,  tokB + (size_t)2*NN*64);
  // hop 3
  k_gather<<<GG, 256, 0, stream>>>(fill, csr_src, dinv, pbuf1, pbuf0);
  k_token <<<GB, 256, 0, stream>>>(pbuf0, wp + WP_SG + 9216, sgb + 128, tokB + (size_t)3*NN*64);

  k_attn<<<2048, 256, 0, stream>>>(tokB, wp, bqkv, bo, ln1w, ln1b);
  k_ffn <<<2048, 256, 0, stream>>>(tokB, wp, b1, b2, ln2w, ln2b, bc, (float*)d_out);
}

// Round 7
// 867.528 us; speedup vs baseline: 3.6219x; 1.0783x over previous
//
#include <hip/hip_runtime.h>
#include <hip/hip_bf16.h>
#include <math.h>

#define NN 100000
#define EE 1600000
#define OUTC 40
#define NB 391            // (NN+255)/256
#define NG 6250           // NN/16 groups for attn/ffn

// prepacked-weight offsets (in shorts), padded to LDS strides
#define WP_WIN 0          // 64 x 264   (Win 64x256)
#define WP_SG  16896      // 3 x 64 x 72 (sgW 3x64x64)
#define WP_QKV 30720      // 192 x 72
#define WP_WO  44544      // 64 x 72
#define WP_W1  49152      // 128 x 72
#define WP_W2  58368      // 64 x 136  (W2 64x128)
#define WP_WC  67072      // 40 x 72
#define WP_TOT 69952

typedef __hip_bfloat16 bf16;
typedef __attribute__((ext_vector_type(8))) short bf16x8;
typedef __attribute__((ext_vector_type(4))) float f32x4;

__device__ __forceinline__ unsigned short f2us(float f){
  bf16 b = __float2bfloat16(f);
  unsigned short u; __builtin_memcpy(&u, &b, 2); return u;
}
__device__ __forceinline__ float us2f(unsigned short u){
  union{unsigned x; float f;} c; c.x = ((unsigned)u)<<16; return c.f;
}
__device__ __forceinline__ float lo_f(unsigned u){ union{unsigned x;float f;}c; c.x = u<<16; return c.f; }
__device__ __forceinline__ float hi_f(unsigned u){ union{unsigned x;float f;}c; c.x = u & 0xffff0000u; return c.f; }

// ---------------- weight prepack (fp32 -> bf16, LDS-image layouts) ----------------
__global__ void k_wprep(const float* __restrict__ Win, const float* __restrict__ sgW,
                        const float* __restrict__ Wqkv, const float* __restrict__ Wo,
                        const float* __restrict__ W1, const float* __restrict__ W2,
                        const float* __restrict__ Wc, unsigned short* __restrict__ wp){
  for (int idx = blockIdx.x*blockDim.x + threadIdx.x; idx < WP_TOT;
       idx += gridDim.x*blockDim.x){
    float v; int o;
    if (idx < WP_SG){ o = idx; int r=o/264, c=o-r*264; v = (c<256)? Win[r*256+c] : 0.f; }
    else if (idx < WP_QKV){ o = idx-WP_SG; int h=o/4608, rem=o-h*4608, r=rem/72, c=rem-r*72;
      v=(c<64)? sgW[h*4096+r*64+c] : 0.f; }
    else if (idx < WP_WO){ o = idx-WP_QKV; int r=o/72, c=o-r*72; v=(c<64)? Wqkv[r*64+c]:0.f; }
    else if (idx < WP_W1){ o = idx-WP_WO; int r=o/72, c=o-r*72; v=(c<64)? Wo[r*64+c]:0.f; }
    else if (idx < WP_W2){ o = idx-WP_W1; int r=o/72, c=o-r*72; v=(c<64)? W1[r*64+c]:0.f; }
    else if (idx < WP_WC){ o = idx-WP_W2; int r=o/136, c=o-r*136; v=(c<128)? W2[r*128+c]:0.f; }
    else { o = idx-WP_WC; int r=o/72, c=o-r*72; v=(c<64)? Wc[r*64+c]:0.f; }
    wp[idx] = f2us(v);
  }
}

// ---------------- CSR build (XCD-partitioned: block r=blockIdx&7 owns node range) ----
__global__ void k_zero(int* cnt){
  int i = blockIdx.x*blockDim.x + threadIdx.x;
  if (i < NN) cnt[i] = 0;
}
__global__ void __launch_bounds__(256) k_cnt8(const int* __restrict__ ei, int* cnt){
  const int r = blockIdx.x & 7;
  const int lo = r*12500, hi = lo + 12500;
  const int nb = gridDim.x >> 3, q = blockIdx.x >> 3;
  for (int e = q*256 + threadIdx.x; e < EE; e += nb*256){
    int d = ei[EE + e];
    if (d >= lo && d < hi) atomicAdd(&cnt[d], 1);
  }
}
__global__ void __launch_bounds__(256) k_bsum(const int* __restrict__ cnt, int* __restrict__ bsum){
  __shared__ int wsum[4];
  int i = blockIdx.x*256 + threadIdx.x;
  int v = (i < NN) ? cnt[i] : 0;
  #pragma unroll
  for (int m = 1; m < 64; m <<= 1) v += __shfl_xor(v, m);
  if ((threadIdx.x & 63) == 0) wsum[threadIdx.x >> 6] = v;
  __syncthreads();
  if (threadIdx.x == 0) bsum[blockIdx.x] = wsum[0] + wsum[1] + wsum[2] + wsum[3];
}
__global__ void __launch_bounds__(512) k_scanb(int* bsum){
  __shared__ int sh[512];
  const int t = threadIdx.x;
  int v = (t < NB) ? bsum[t] : 0;
  sh[t] = v;
  __syncthreads();
  int acc = v;
  for (int st = 1; st < 512; st <<= 1){
    int add = (t >= st) ? sh[t - st] : 0;
    __syncthreads();
    acc += add; sh[t] = acc;
    __syncthreads();
  }
  if (t < NB) bsum[t] = acc - v;   // exclusive
}
__global__ void __launch_bounds__(256) k_scan2(const int* __restrict__ cnt,
    const int* __restrict__ bsum, int* __restrict__ fill, float* __restrict__ dinv){
  __shared__ int sh[256];
  const int t = threadIdx.x;
  int i = blockIdx.x*256 + t;
  int c = (i < NN) ? cnt[i] : 0;
  sh[t] = c;
  __syncthreads();
  int acc = c;
  for (int st = 1; st < 256; st <<= 1){
    int add = (t >= st) ? sh[t - st] : 0;
    __syncthreads();
    acc += add; sh[t] = acc;
    __syncthreads();
  }
  if (i < NN){
    fill[i] = bsum[blockIdx.x] + acc - c;
    dinv[i] = rsqrtf((float)c + 1.0f);
  }
}
__global__ void __launch_bounds__(256) k_fill8(const int* __restrict__ ei,
                                               int* fill, int* csr_src){
  const int r = blockIdx.x & 7;
  const int lo = r*12500, hi = lo + 12500;
  const int nb = gridDim.x >> 3, q = blockIdx.x >> 3;
  for (int e = q*256 + threadIdx.x; e < EE; e += nb*256){
    int d = ei[EE + e];
    if (d >= lo && d < hi){
      int p = atomicAdd(&fill[d], 1);
      csr_src[p] = ei[e];
    }
  }
}

// ------- gather propagation (bf16 rows, fp32 accumulate): cur = S @ prev -------
__global__ void __launch_bounds__(256) k_gather(const int* __restrict__ fill,
    const int* __restrict__ csr_src, const float* __restrict__ dinv,
    const unsigned short* __restrict__ prev, unsigned short* __restrict__ cur){
  int wid = (blockIdx.x*256 + threadIdx.x) >> 6;
  int lane = threadIdx.x & 63;
  if (wid >= NN) return;
  const int n = wid;
  int b = (n == 0) ? 0 : fill[n-1];
  int e = fill[n];
  float dn = dinv[n];
  float acc = us2f(prev[(size_t)n*64 + lane]) * dn * dn;
  for (int base = b; base < e; base += 64){
    int idx = base + lane;
    int sv = 0; float wv = 0.f;
    if (idx < e){ sv = csr_src[idx]; wv = dinv[sv] * dn; }
    int m = min(64, e - base);
    for (int j = 0; j < m; ++j){
      int s = __shfl(sv, j);
      float w = __shfl(wv, j);
      acc += us2f(prev[(size_t)s*64 + lane]) * w;
    }
  }
  cur[(size_t)n*64 + lane] = f2us(acc);
}

// ------- h0 = relu(x @ W_in^T + b_in) -> tok0 (bf16) and p0 (bf16) -------
__global__ void __launch_bounds__(256) k_h0(const float* __restrict__ x,
    const unsigned short* __restrict__ wp, const float* __restrict__ bin,
    unsigned short* __restrict__ tokB, unsigned short* __restrict__ p0){
  __shared__ __align__(16) unsigned short Xs[64*264];
  __shared__ __align__(16) unsigned short Ws[64*264];
  __shared__ float bs[64];
  const int tid = threadIdx.x;
  {
    const uint4* src = (const uint4*)(wp + WP_WIN);
    for (int idx = tid; idx < 2112; idx += 256) ((uint4*)Ws)[idx] = src[idx];
  }
  const int n0 = blockIdx.x * 64;
  for (int idx = tid; idx < 4096; idx += 256){       // X tile: 64x256, fp32->bf16
    int r = idx >> 6, c0 = (idx & 63) * 4;
    int n = n0 + r; if (n >= NN) n = NN-1;
    float4 v = *(const float4*)(x + (size_t)n*256 + c0);
    unsigned short* d = &Xs[r*264 + c0];
    d[0]=f2us(v.x); d[1]=f2us(v.y); d[2]=f2us(v.z); d[3]=f2us(v.w);
  }
  if (tid < 64) bs[tid] = bin[tid];
  __syncthreads();
  const int w = tid >> 6, lane = tid & 63, quad = lane >> 4, c = lane & 15;
  f32x4 acc[4] = {{0,0,0,0},{0,0,0,0},{0,0,0,0},{0,0,0,0}};
  #pragma unroll
  for (int ks = 0; ks < 8; ++ks){
    int k0 = ks*32 + quad*8;
    bf16x8 a = *(const bf16x8*)&Xs[(w*16 + c)*264 + k0];
    #pragma unroll
    for (int nt = 0; nt < 4; ++nt){
      bf16x8 b = *(const bf16x8*)&Ws[(nt*16 + c)*264 + k0];
      acc[nt] = __builtin_amdgcn_mfma_f32_16x16x32_bf16(a, b, acc[nt], 0,0,0);
    }
  }
  __syncthreads();
  #pragma unroll
  for (int nt = 0; nt < 4; ++nt){
    int col = nt*16 + c;
    float bb = bs[col];
    #pragma unroll
    for (int rg = 0; rg < 4; ++rg){
      int rloc = w*16 + quad*4 + rg;
      Xs[rloc*72 + col] = f2us(fmaxf(acc[nt][rg] + bb, 0.f));
    }
  }
  __syncthreads();
  for (int idx = tid; idx < 512; idx += 256){
    int r = idx >> 3, ch = idx & 7;
    int n = n0 + r;
    if (n < NN){
      uint4 v = *(const uint4*)&Xs[r*72 + ch*8];
      *(uint4*)(tokB + (size_t)n*64 + ch*8) = v;
      *(uint4*)(p0   + (size_t)n*64 + ch*8) = v;
    }
  }
}

// ------- token = relu(cur @ sgW^T + sgb) -> bf16 tokens (cur is bf16) -------
__global__ void __launch_bounds__(256) k_token(const unsigned short* __restrict__ cur,
    const unsigned short* __restrict__ wsg, const float* __restrict__ sgb,
    unsigned short* __restrict__ tok){
  __shared__ __align__(16) unsigned short Xs[64*72];
  __shared__ __align__(16) unsigned short Ws[64*72];
  __shared__ float bs[64];
  const int tid = threadIdx.x;
  {
    const uint4* src = (const uint4*)wsg;
    for (int idx = tid; idx < 576; idx += 256) ((uint4*)Ws)[idx] = src[idx];
  }
  if (tid < 64) bs[tid] = sgb[tid];
  const int n0 = blockIdx.x*64;
  for (int idx = tid; idx < 512; idx += 256){
    int r = idx >> 3, ch = idx & 7;
    int n = n0 + r; if (n >= NN) n = NN-1;
    *(uint4*)&Xs[r*72 + ch*8] = *(const uint4*)(cur + (size_t)n*64 + ch*8);
  }
  __syncthreads();
  const int w = tid >> 6, lane = tid & 63, quad = lane >> 4, c = lane & 15;
  f32x4 acc[4] = {{0,0,0,0},{0,0,0,0},{0,0,0,0},{0,0,0,0}};
  #pragma unroll
  for (int ks = 0; ks < 2; ++ks){
    int k0 = ks*32 + quad*8;
    bf16x8 a = *(const bf16x8*)&Xs[(w*16 + c)*72 + k0];
    #pragma unroll
    for (int nt = 0; nt < 4; ++nt){
      bf16x8 b = *(const bf16x8*)&Ws[(nt*16 + c)*72 + k0];
      acc[nt] = __builtin_amdgcn_mfma_f32_16x16x32_bf16(a, b, acc[nt], 0,0,0);
    }
  }
  __syncthreads();
  #pragma unroll
  for (int nt = 0; nt < 4; ++nt){
    int col = nt*16 + c;
    float bb = bs[col];
    #pragma unroll
    for (int rg = 0; rg < 4; ++rg){
      int rloc = w*16 + quad*4 + rg;
      Xs[rloc*72 + col] = f2us(fmaxf(acc[nt][rg] + bb, 0.f));
    }
  }
  __syncthreads();
  for (int idx = tid; idx < 512; idx += 256){
    int r = idx >> 3, ch = idx & 7;
    int n = n0 + r;
    if (n < NN)
      *(uint4*)(tok + (size_t)n*64 + ch*8) = *(const uint4*)&Xs[r*72 + ch*8];
  }
}

// ---------------- attention + LN1 (persistent, bf16 tokens in-place) ----------------
__global__ void __launch_bounds__(256) k_attn(unsigned short* __restrict__ tokB,
    const unsigned short* __restrict__ wp, const float* __restrict__ bqkv,
    const float* __restrict__ bo, const float* __restrict__ ln1w,
    const float* __restrict__ ln1b){
  __shared__ __align__(16) unsigned short Wq[192*72];
  __shared__ __align__(16) unsigned short Wos[64*72];
  __shared__ __align__(16) unsigned short Xs[64*72];
  __shared__ __align__(16) unsigned short As2[64*72];
  __shared__ float bq[192], bos[64], l1w[64], l1b[64];
  const int tid = threadIdx.x;
  {
    const uint4* s1 = (const uint4*)(wp + WP_QKV);
    for (int idx = tid; idx < 1728; idx += 256) ((uint4*)Wq)[idx] = s1[idx];
    const uint4* s2 = (const uint4*)(wp + WP_WO);
    for (int idx = tid; idx < 576; idx += 256) ((uint4*)Wos)[idx] = s2[idx];
  }
  if (tid < 192) bq[tid] = bqkv[tid];
  if (tid < 64){ bos[tid]=bo[tid]; l1w[tid]=ln1w[tid]; l1b[tid]=ln1b[tid]; }
  const int w = tid >> 6, lane = tid & 63, quad = lane >> 4, c = lane & 15;
  const int rw = w*16;
  for (int g = blockIdx.x; g < NG; g += gridDim.x){
    __syncthreads();        // protect Xs/As2 from previous iteration readers
    for (int idx = tid; idx < 512; idx += 256){     // stage 64 rows of bf16 tokens
      int r = idx >> 3, ch = idx & 7;
      int t = r & 3, n = g*16 + (r >> 2);           // row = node_local*4 + t
      *(uint4*)&Xs[r*72 + ch*8] = *(const uint4*)(tokB + ((size_t)t*NN + n)*64 + ch*8);
    }
    __syncthreads();
    bf16x8 a0 = *(const bf16x8*)&Xs[(rw+c)*72 + quad*8];
    bf16x8 a1 = *(const bf16x8*)&Xs[(rw+c)*72 + 32 + quad*8];
    f32x4 qk[12];   // 0-3: q tiles, 4-7: k tiles, 8-11: v tiles
    #pragma unroll
    for (int nt = 0; nt < 12; ++nt){
      f32x4 acc = {0,0,0,0};
      bf16x8 b0 = *(const bf16x8*)&Wq[(nt*16+c)*72 + quad*8];
      bf16x8 b1 = *(const bf16x8*)&Wq[(nt*16+c)*72 + 32 + quad*8];
      acc = __builtin_amdgcn_mfma_f32_16x16x32_bf16(a0, b0, acc, 0,0,0);
      acc = __builtin_amdgcn_mfma_f32_16x16x32_bf16(a1, b1, acc, 0,0,0);
      float bb = bq[nt*16 + c];
      acc[0]+=bb; acc[1]+=bb; acc[2]+=bb; acc[3]+=bb;
      qk[nt] = acc;
    }
    float sc[4][4];
    #pragma unroll
    for (int s = 0; s < 4; ++s){
      #pragma unroll
      for (int t = 0; t < 4; ++t){
        float p = qk[0][s]*qk[4][t] + qk[1][s]*qk[5][t]
                + qk[2][s]*qk[6][t] + qk[3][s]*qk[7][t];
        p += __shfl_xor(p, 1); p += __shfl_xor(p, 2);
        p += __shfl_xor(p, 4); p += __shfl_xor(p, 8);
        sc[s][t] = p * 0.125f;
      }
    }
    float pm[4][4];
    #pragma unroll
    for (int s = 0; s < 4; ++s){
      float m = fmaxf(fmaxf(sc[s][0],sc[s][1]), fmaxf(sc[s][2],sc[s][3]));
      float e0=__expf(sc[s][0]-m), e1=__expf(sc[s][1]-m);
      float e2=__expf(sc[s][2]-m), e3=__expf(sc[s][3]-m);
      float inv = 1.f/(e0+e1+e2+e3);
      pm[s][0]=e0*inv; pm[s][1]=e1*inv; pm[s][2]=e2*inv; pm[s][3]=e3*inv;
    }
    // P@V -> As2 in A-layout (wave-private rows)
    #pragma unroll
    for (int tile = 0; tile < 4; ++tile){
      #pragma unroll
      for (int s = 0; s < 4; ++s){
        float av = pm[s][0]*qk[8+tile][0] + pm[s][1]*qk[8+tile][1]
                 + pm[s][2]*qk[8+tile][2] + pm[s][3]*qk[8+tile][3];
        As2[(rw + quad*4 + s)*72 + tile*16 + c] = f2us(av);
      }
    }
    bf16x8 p0 = *(const bf16x8*)&As2[(rw+c)*72 + quad*8];
    bf16x8 p1 = *(const bf16x8*)&As2[(rw+c)*72 + 32 + quad*8];
    f32x4 ov[4];
    #pragma unroll
    for (int nt = 0; nt < 4; ++nt){
      f32x4 acc = {0,0,0,0};
      bf16x8 b0 = *(const bf16x8*)&Wos[(nt*16+c)*72 + quad*8];
      bf16x8 b1 = *(const bf16x8*)&Wos[(nt*16+c)*72 + 32 + quad*8];
      acc = __builtin_amdgcn_mfma_f32_16x16x32_bf16(p0, b0, acc, 0,0,0);
      acc = __builtin_amdgcn_mfma_f32_16x16x32_bf16(p1, b1, acc, 0,0,0);
      ov[nt] = acc;
    }
    float r4[4][4];
    #pragma unroll
    for (int nt = 0; nt < 4; ++nt){
      int col = nt*16 + c;
      float bb = bos[col];
      #pragma unroll
      for (int rg = 0; rg < 4; ++rg){
        float seqv = us2f(Xs[(rw + quad*4 + rg)*72 + col]);
        r4[nt][rg] = ov[nt][rg] + bb + seqv;
      }
    }
    #pragma unroll
    for (int rg = 0; rg < 4; ++rg){
      float sm = r4[0][rg]+r4[1][rg]+r4[2][rg]+r4[3][rg];
      sm += __shfl_xor(sm,1); sm += __shfl_xor(sm,2);
      sm += __shfl_xor(sm,4); sm += __shfl_xor(sm,8);
      float mean = sm * (1.f/64.f);
      float d0=r4[0][rg]-mean, d1=r4[1][rg]-mean, d2=r4[2][rg]-mean, d3=r4[3][rg]-mean;
      float vs = d0*d0+d1*d1+d2*d2+d3*d3;
      vs += __shfl_xor(vs,1); vs += __shfl_xor(vs,2);
      vs += __shfl_xor(vs,4); vs += __shfl_xor(vs,8);
      float rinv = rsqrtf(vs*(1.f/64.f) + 1e-5f);
      int row = rw + quad*4 + rg;
      #pragma unroll
      for (int nt = 0; nt < 4; ++nt){
        int col = nt*16 + c;
        As2[row*72 + col] = f2us((r4[nt][rg] - mean) * rinv * l1w[col] + l1b[col]);
      }
    }
    __syncthreads();
    for (int idx = tid; idx < 512; idx += 256){     // coalesced copy-out
      int r = idx >> 3, ch = idx & 7;
      int t = r & 3, n = g*16 + (r >> 2);
      *(uint4*)(tokB + ((size_t)t*NN + n)*64 + ch*8) = *(const uint4*)&As2[r*72 + ch*8];
    }
  }
}

// ---------------- FFN + LN2 + mean + classifier (persistent) ----------------
__global__ void __launch_bounds__(256) k_ffn(const unsigned short* __restrict__ tokB,
    const unsigned short* __restrict__ wp,
    const float* __restrict__ b1, const float* __restrict__ b2,
    const float* __restrict__ ln2w, const float* __restrict__ ln2b,
    const float* __restrict__ bc, float* __restrict__ out){
  __shared__ __align__(16) unsigned short W1s[128*72];
  __shared__ __align__(16) unsigned short W2s[64*136];
  __shared__ __align__(16) unsigned short Wcs[40*72];
  __shared__ __align__(16) unsigned short Xs[64*72];
  __shared__ __align__(16) unsigned short F1[64*136];
  __shared__ float hs[16*68];
  __shared__ float b1s[128], b2s[64], l2w[64], l2b[64], bcs[40];
  const int tid = threadIdx.x;
  {
    const uint4* s1 = (const uint4*)(wp + WP_W1);
    for (int idx = tid; idx < 1152; idx += 256) ((uint4*)W1s)[idx] = s1[idx];
    const uint4* s2 = (const uint4*)(wp + WP_W2);
    for (int idx = tid; idx < 1088; idx += 256) ((uint4*)W2s)[idx] = s2[idx];
    const uint4* s3 = (const uint4*)(wp + WP_WC);
    for (int idx = tid; idx < 360; idx += 256) ((uint4*)Wcs)[idx] = s3[idx];
  }
  if (tid < 128) b1s[tid] = b1[tid];
  if (tid < 64){ b2s[tid]=b2[tid]; l2w[tid]=ln2w[tid]; l2b[tid]=ln2b[tid]; }
  if (tid < 40)  bcs[tid] = bc[tid];
  const int w = tid >> 6, lane = tid & 63, quad = lane >> 4, c = lane & 15;
  const int rw = w*16;
  for (int g = blockIdx.x; g < NG; g += gridDim.x){
    __syncthreads();
    for (int idx = tid; idx < 512; idx += 256){
      int r = idx >> 3, ch = idx & 7;
      int t = r & 3, n = g*16 + (r >> 2);
      *(uint4*)&Xs[r*72 + ch*8] = *(const uint4*)(tokB + ((size_t)t*NN + n)*64 + ch*8);
    }
    __syncthreads();
    bf16x8 a0 = *(const bf16x8*)&Xs[(rw+c)*72 + quad*8];
    bf16x8 a1 = *(const bf16x8*)&Xs[(rw+c)*72 + 32 + quad*8];
    // ff1 + exact gelu -> F1 (A-layout bf16, wave-private rows)
    #pragma unroll
    for (int nt = 0; nt < 8; ++nt){
      f32x4 acc = {0,0,0,0};
      bf16x8 b0 = *(const bf16x8*)&W1s[(nt*16+c)*72 + quad*8];
      bf16x8 b1v = *(const bf16x8*)&W1s[(nt*16+c)*72 + 32 + quad*8];
      acc = __builtin_amdgcn_mfma_f32_16x16x32_bf16(a0, b0, acc, 0,0,0);
      acc = __builtin_amdgcn_mfma_f32_16x16x32_bf16(a1, b1v, acc, 0,0,0);
      float bb = b1s[nt*16 + c];
      #pragma unroll
      for (int rg = 0; rg < 4; ++rg){
        float v = acc[rg] + bb;
        float ge = 0.5f * v * (1.f + erff(v * 0.70710678118654752f));
        F1[(rw + quad*4 + rg)*136 + nt*16 + c] = f2us(ge);
      }
    }
    // ff2 (same-wave LDS in-order)
    bf16x8 fa[4];
    #pragma unroll
    for (int ks = 0; ks < 4; ++ks)
      fa[ks] = *(const bf16x8*)&F1[(rw+c)*136 + ks*32 + quad*8];
    f32x4 ov[4];
    #pragma unroll
    for (int nt = 0; nt < 4; ++nt){
      f32x4 acc = {0,0,0,0};
      #pragma unroll
      for (int ks = 0; ks < 4; ++ks){
        bf16x8 b = *(const bf16x8*)&W2s[(nt*16+c)*136 + ks*32 + quad*8];
        acc = __builtin_amdgcn_mfma_f32_16x16x32_bf16(fa[ks], b, acc, 0,0,0);
      }
      ov[nt] = acc;
    }
    float r4[4][4];
    #pragma unroll
    for (int nt = 0; nt < 4; ++nt){
      int col = nt*16 + c;
      float bb = b2s[col];
      #pragma unroll
      for (int rg = 0; rg < 4; ++rg){
        float seqv = us2f(Xs[(rw + quad*4 + rg)*72 + col]);
        r4[nt][rg] = ov[nt][rg] + bb + seqv;
      }
    }
    float hval[4] = {0.f, 0.f, 0.f, 0.f};
    #pragma unroll
    for (int rg = 0; rg < 4; ++rg){
      float sm = r4[0][rg]+r4[1][rg]+r4[2][rg]+r4[3][rg];
      sm += __shfl_xor(sm,1); sm += __shfl_xor(sm,2);
      sm += __shfl_xor(sm,4); sm += __shfl_xor(sm,8);
      float mean = sm * (1.f/64.f);
      float d0=r4[0][rg]-mean, d1=r4[1][rg]-mean, d2=r4[2][rg]-mean, d3=r4[3][rg]-mean;
      float vs = d0*d0+d1*d1+d2*d2+d3*d3;
      vs += __shfl_xor(vs,1); vs += __shfl_xor(vs,2);
      vs += __shfl_xor(vs,4); vs += __shfl_xor(vs,8);
      float rinv = rsqrtf(vs*(1.f/64.f) + 1e-5f);
      #pragma unroll
      for (int nt = 0; nt < 4; ++nt){
        int col = nt*16 + c;
        hval[nt] += (r4[nt][rg] - mean) * rinv * l2w[col] + l2b[col];
      }
    }
    #pragma unroll
    for (int nt = 0; nt < 4; ++nt)
      hs[(w*4 + quad)*68 + nt*16 + c] = hval[nt] * 0.25f;
    __syncthreads();
    for (int p = tid; p < 16*OUTC; p += 256){
      int node = p / OUTC, o = p - node*OUTC;
      float acc = bcs[o];
      const unsigned* wrow = (const unsigned*)&Wcs[o*72];
      const float2*  hrow = (const float2*)&hs[node*68];
      #pragma unroll 8
      for (int j2 = 0; j2 < 32; ++j2){
        unsigned u = wrow[j2];
        float2 hv = hrow[j2];
        acc += hv.x*lo_f(u) + hv.y*hi_f(u);
      }
      out[(size_t)(g*16 + node)*OUTC + o] = acc;
    }
  }
}

extern "C" void kernel_launch(void* const* d_in, const int* in_sizes, int n_in,
                              void* d_out, int out_size, void* d_ws, size_t ws_size,
                              hipStream_t stream) {
  const float* x    = (const float*)d_in[0];
  const int*   ei   = (const int*  )d_in[1];
  const float* Win  = (const float*)d_in[2];
  const float* bin  = (const float*)d_in[3];
  const float* sgW  = (const float*)d_in[4];
  const float* sgb  = (const float*)d_in[5];
  const float* Wqkv = (const float*)d_in[6];
  const float* bqkv = (const float*)d_in[7];
  const float* Wo   = (const float*)d_in[8];
  const float* bo   = (const float*)d_in[9];
  const float* W1   = (const float*)d_in[10];
  const float* b1   = (const float*)d_in[11];
  const float* W2   = (const float*)d_in[12];
  const float* b2   = (const float*)d_in[13];
  const float* ln1w = (const float*)d_in[14];
  const float* ln1b = (const float*)d_in[15];
  const float* ln2w = (const float*)d_in[16];
  const float* ln2b = (const float*)d_in[17];
  const float* Wc   = (const float*)d_in[18];
  const float* bc   = (const float*)d_in[19];

  char* ws = (char*)d_ws;
  float*          dinv = (float*)(ws);                      // 400,000 B
  int*            fill = (int*  )(ws + 400128);             // 400,000 B
  unsigned short* wp   = (unsigned short*)(ws + 800256);    // 139,904 B prepacked weights
  unsigned short* tokB = (unsigned short*)(ws + 940288);    // 4*N*64*2 = 51,200,000 B
  unsigned short* pb0  = (unsigned short*)(ws + 52140416);  // 12,800,000 B (bf16 p)
  unsigned short* pb1  = (unsigned short*)(ws + 64940544);  // 12,800,000 B
  // CSR scratch aliased into the (not-yet-written) hop-3 token slot (12.8 MB):
  int* csr_src = (int*)(tokB + (size_t)3*NN*64);            // 6.4 MB
  int* cnt     = csr_src + EE;                              // 400 KB
  int* bsum    = cnt + NN;                                  // ~1.6 KB

  k_wprep<<<128, 256, 0, stream>>>(Win, sgW, Wqkv, Wo, W1, W2, Wc, wp);

  // --- CSR build (once; reused by all 3 hops), XCD-partitioned ---
  k_zero <<<(NN+255)/256, 256, 0, stream>>>(cnt);
  k_cnt8 <<<6256, 256, 0, stream>>>(ei, cnt);
  k_bsum <<<NB, 256, 0, stream>>>(cnt, bsum);
  k_scanb<<<1, 512, 0, stream>>>(bsum);
  k_scan2<<<NB, 256, 0, stream>>>(cnt, bsum, fill, dinv);
  k_fill8<<<6256, 256, 0, stream>>>(ei, fill, csr_src);

  const int GB = (NN + 63) / 64;                   // 1563
  const int GG = (NN*64 + 255) / 256;              // 25000 (wave per node)
  k_h0<<<GB, 256, 0, stream>>>(x, wp, bin, tokB, pb0);

  // hop 1
  k_gather<<<GG, 256, 0, stream>>>(fill, csr_src, dinv, pb0, pb1);
  k_token <<<GB, 256, 0, stream>>>(pb1, wp + WP_SG,        sgb,       tokB + (size_t)1*NN*64);
  // hop 2
  k_gather<<<GG, 256, 0, stream>>>(fill, csr_src, dinv, pb1, pb0);
  k_token <<<GB, 256, 0, stream>>>(pb0, wp + WP_SG + 4608, sgb + 64,  tokB + (size_t)2*NN*64);
  // hop 3
  k_gather<<<GG, 256, 0, stream>>>(fill, csr_src, dinv, pb0, pb1);
  k_token <<<GB, 256, 0, stream>>>(pb1, wp + WP_SG + 9216, sgb + 128, tokB + (size_t)3*NN*64);

  k_attn<<<2048, 256, 0, stream>>>(tokB, wp, bqkv, bo, ln1w, ln1b);
  k_ffn <<<2048, 256, 0, stream>>>(tokB, wp, b1, b2, ln2w, ln2b, bc, (float*)d_out);
}